// Round 9
// baseline (350.070 us; speedup 1.0000x reference)
//
#include <hip/hip_runtime.h>
#include <hip/hip_bf16.h>

// Problem constants
#define BB 4
#define TT 2048
#define CCH 1024
#define NHH 16
#define HSS 64
#define MROWS (BB * TT)            // 8192
#define QKV_ELEMS (64 * 2048 * 64) // per-tensor elems = 8388608

typedef __attribute__((ext_vector_type(8))) short short8;
typedef __attribute__((ext_vector_type(4))) float f32x4;

#define CVTPK(d, a, b) asm("v_cvt_pk_bf16_f32 %0, %1, %2" : "=v"(d) : "v"(a), "v"(b))

static __device__ __forceinline__ unsigned short bf16_of(float f) {
  union { float f; unsigned u; } v; v.f = f;
  unsigned u = v.u;
  return (unsigned short)((u + 0x7FFFu + ((u >> 16) & 1u)) >> 16);
}

// ---------------- cast kernels ----------------
__global__ __launch_bounds__(256) void cast_f32_bf16(const float* __restrict__ in,
                                                     unsigned short* __restrict__ out, int n) {
  int i = (blockIdx.x * 256 + threadIdx.x) * 4;
  if (i < n) {
    float4 f = *reinterpret_cast<const float4*>(in + i);
    ushort4 o;
    o.x = bf16_of(f.x); o.y = bf16_of(f.y); o.z = bf16_of(f.z); o.w = bf16_of(f.w);
    *reinterpret_cast<ushort4*>(out + i) = o;
  }
}

// in: [K][N] f32 row-major -> out: [N][K] bf16 row-major
__global__ __launch_bounds__(256) void transpose_cast(const float* __restrict__ in,
                                                      unsigned short* __restrict__ out,
                                                      int K, int N) {
  int idx = blockIdx.x * 256 + threadIdx.x;
  if (idx < K * N) {
    int k = idx / N;
    int n = idx - k * N;
    out[(size_t)n * K + k] = bf16_of(in[idx]);
  }
}

// ---------------- GEMM: C = A[M,K] @ Bt[N,K]^T + bias (verified R1-R3) ----------------
template <int MODE>
__global__ __launch_bounds__(256) void gemm_bt(const unsigned short* __restrict__ A,
                                               const unsigned short* __restrict__ Bt,
                                               const float* __restrict__ bias,
                                               float* __restrict__ outF,
                                               unsigned short* __restrict__ outQKV,
                                               int M, int N, int K) {
  __shared__ unsigned short As[128 * 32];
  __shared__ unsigned short Bs[128 * 32];
  int tid = threadIdx.x;
  int w = tid >> 6, lane = tid & 63;
  int g = lane >> 4, r16 = lane & 15;
  int wr = w >> 1, wc = w & 1;
  int m0 = blockIdx.y * 128, n0 = blockIdx.x * 128;
  int lrow = lane >> 2;
  int lcol = (lane & 3) * 8;

  f32x4 zero = {0.f, 0.f, 0.f, 0.f};
  f32x4 acc[4][4];
#pragma unroll
  for (int i = 0; i < 4; ++i)
#pragma unroll
    for (int n = 0; n < 4; ++n) acc[i][n] = zero;

  for (int kt = 0; kt < K; kt += 32) {
#pragma unroll
    for (int c = 0; c < 2; ++c) {
      int rg = w * 32 + c * 16;
      __builtin_amdgcn_global_load_lds(
          (const __attribute__((address_space(1))) void*)(&A[(size_t)(m0 + rg + lrow) * K + kt + lcol]),
          (__attribute__((address_space(3))) void*)(&As[rg * 32]), 16, 0, 0);
      __builtin_amdgcn_global_load_lds(
          (const __attribute__((address_space(1))) void*)(&Bt[(size_t)(n0 + rg + lrow) * K + kt + lcol]),
          (__attribute__((address_space(3))) void*)(&Bs[rg * 32]), 16, 0, 0);
    }
    __syncthreads();
    short8 af[4], bfr[4];
#pragma unroll
    for (int i = 0; i < 4; ++i)
      af[i] = *reinterpret_cast<const short8*>(&As[(wr * 64 + i * 16 + r16) * 32 + g * 8]);
#pragma unroll
    for (int i = 0; i < 4; ++i)
      bfr[i] = *reinterpret_cast<const short8*>(&Bs[(wc * 64 + i * 16 + r16) * 32 + g * 8]);
#pragma unroll
    for (int i = 0; i < 4; ++i)
#pragma unroll
      for (int n = 0; n < 4; ++n)
        acc[i][n] = __builtin_amdgcn_mfma_f32_16x16x32_bf16(af[i], bfr[n], acc[i][n], 0, 0, 0);
    __syncthreads();
  }

#pragma unroll
  for (int i = 0; i < 4; ++i)
#pragma unroll
    for (int n = 0; n < 4; ++n)
#pragma unroll
      for (int j = 0; j < 4; ++j) {
        int row = m0 + wr * 64 + i * 16 + g * 4 + j;
        int col = n0 + wc * 64 + n * 16 + r16;
        float val = acc[i][n][j] + bias[col];
        if (MODE == 0) {
          outF[(size_t)row * N + col] = val;
        } else {
          int which = col >> 10, c = col & 1023;
          int h = c >> 6, d = c & 63;
          int b = row >> 11, t = row & 2047;
          if (which == 2) {
            outQKV[2 * (size_t)QKV_ELEMS +
                   (((size_t)(b * 16 + h) * 64 + d) * 2048 + t)] = bf16_of(val);
          } else {
            if (which == 0) val *= 0.125f;   // fold 1/sqrt(HS) into Q (exact pow2)
            outQKV[(size_t)which * QKV_ELEMS +
                   (((size_t)(b * 16 + h) * 2048 + t) * 64 + d)] = bf16_of(val);
          }
        }
      }
}

// ---------------- causal flash attention: shuffle-free PV via permuted V ----------------
// Swapped QK^T on verified 16x16x32 layouts. PV B-frag keeps the lane's own
// p-values (key bijection sigma(g4,j) = 4g4+j / 16+4g4+(j-4)); V^T A-frag is
// loaded with the SAME sigma (two 8B loads per d-block) -> zero cross-lane ops
// in the P path. Balanced chunk pairs {c, 63-c}: every wave 65 tiles, 130 computes.
struct Frags {
  short8 kf0[2], kf1[2];
  union VU { int w[4]; short8 s8; } vf[4];
};

static __device__ __forceinline__ void load_frags(Frags& f, int key0, int r16, int g4,
                                                  const unsigned short* __restrict__ Kp,
                                                  const unsigned short* __restrict__ Vp) {
#pragma unroll
  for (int c = 0; c < 2; ++c)
    f.kf0[c] = *reinterpret_cast<const short8*>(&Kp[(size_t)(key0 + r16) * 64 + c * 32 + g4 * 8]);
#pragma unroll
  for (int c = 0; c < 2; ++c)
    f.kf1[c] = *reinterpret_cast<const short8*>(&Kp[(size_t)(key0 + 16 + r16) * 64 + c * 32 + g4 * 8]);
#pragma unroll
  for (int dblk = 0; dblk < 4; ++dblk) {
    const unsigned short* vrow = &Vp[(size_t)(dblk * 16 + r16) * TT + key0 + 4 * g4];
    int2 lo = *reinterpret_cast<const int2*>(vrow);        // keys key0+4g4+{0..3}
    int2 hi = *reinterpret_cast<const int2*>(vrow + 16);   // keys key0+16+4g4+{0..3}
    f.vf[dblk].w[0] = lo.x; f.vf[dblk].w[1] = lo.y;
    f.vf[dblk].w[2] = hi.x; f.vf[dblk].w[3] = hi.y;
  }
}

// MODE 0: full 32-key tile. MODE 1: kb0 full + kb1 diag. MODE 2: kb0 diag only.
template <int MODE>
static __device__ __forceinline__ void compute_tile(const Frags& f, int r16, int g4,
                                                    const short8 qf[2], f32x4 o[4],
                                                    float& m, float& lsum) {
  f32x4 zero = {0.f, 0.f, 0.f, 0.f};
  f32x4 s0 = zero, s1 = zero;
  __builtin_amdgcn_s_setprio(1);
  s0 = __builtin_amdgcn_mfma_f32_16x16x32_bf16(f.kf0[0], qf[0], s0, 0, 0, 0);
  s0 = __builtin_amdgcn_mfma_f32_16x16x32_bf16(f.kf0[1], qf[1], s0, 0, 0, 0);
  if (MODE != 2) {
    s1 = __builtin_amdgcn_mfma_f32_16x16x32_bf16(f.kf1[0], qf[0], s1, 0, 0, 0);
    s1 = __builtin_amdgcn_mfma_f32_16x16x32_bf16(f.kf1[1], qf[1], s1, 0, 0, 0);
  }
  __builtin_amdgcn_s_setprio(0);

  if (MODE == 2) {
#pragma unroll
    for (int r = 0; r < 4; ++r)
      if (g4 * 4 + r > r16) s0[r] = -1e30f;
  }
  if (MODE == 1) {
#pragma unroll
    for (int r = 0; r < 4; ++r)
      if (g4 * 4 + r > r16) s1[r] = -1e30f;
  }

  float om = fmaxf(fmaxf(s0[0], s0[1]), fmaxf(s0[2], s0[3]));
  if (MODE != 2)
    om = fmaxf(om, fmaxf(fmaxf(s1[0], s1[1]), fmaxf(s1[2], s1[3])));
  om = fmaxf(om, __shfl_xor(om, 16));
  om = fmaxf(om, __shfl_xor(om, 32));
  float mn = fmaxf(m, om);
  float alpha = __expf(m - mn);
  m = mn;

  float p0[4], p1[4];
#pragma unroll
  for (int r = 0; r < 4; ++r) {
    p0[r] = __expf(s0[r] - mn);
    if (MODE != 2) p1[r] = __expf(s1[r] - mn);
  }
  float rs = (p0[0] + p0[1]) + (p0[2] + p0[3]);
  if (MODE != 2) rs += (p1[0] + p1[1]) + (p1[2] + p1[3]);
  rs += __shfl_xor(rs, 16);
  rs += __shfl_xor(rs, 32);
  lsum = lsum * alpha + rs;
#pragma unroll
  for (int dblk = 0; dblk < 4; ++dblk)
#pragma unroll
    for (int r = 0; r < 4; ++r) o[dblk][r] *= alpha;

  // P B-fragment from the lane's OWN values (sigma-permuted key order)
  union { int w[4]; short8 s8; } pf;
  CVTPK(pf.w[0], p0[0], p0[1]);
  CVTPK(pf.w[1], p0[2], p0[3]);
  if (MODE != 2) {
    CVTPK(pf.w[2], p1[0], p1[1]);
    CVTPK(pf.w[3], p1[2], p1[3]);
  } else {
    pf.w[2] = 0; pf.w[3] = 0;
  }

  __builtin_amdgcn_s_setprio(1);
#pragma unroll
  for (int dblk = 0; dblk < 4; ++dblk)
    o[dblk] = __builtin_amdgcn_mfma_f32_16x16x32_bf16(f.vf[dblk].s8, pf.s8, o[dblk], 0, 0, 0);
  __builtin_amdgcn_s_setprio(0);
}

// one 32-row q-chunk (rows Q0..Q0+31), tiles 0..c inclusive
static __device__ __forceinline__ void do_chunk(int c, int r16, int g4,
                                                const unsigned short* __restrict__ Qp,
                                                const unsigned short* __restrict__ Kp,
                                                const unsigned short* __restrict__ Vp,
                                                unsigned short* __restrict__ Y,
                                                int b, int h) {
  int Q0 = c * 32;
  short8 qf[2][2];
#pragma unroll
  for (int ss = 0; ss < 2; ++ss)
#pragma unroll
    for (int cc = 0; cc < 2; ++cc)
      qf[ss][cc] = *reinterpret_cast<const short8*>(
          &Qp[(size_t)(Q0 + ss * 16 + r16) * 64 + cc * 32 + g4 * 8]);

  f32x4 o[2][4];
#pragma unroll
  for (int ss = 0; ss < 2; ++ss)
#pragma unroll
    for (int dblk = 0; dblk < 4; ++dblk) o[ss][dblk] = f32x4{0.f, 0.f, 0.f, 0.f};
  float m[2] = {-1e30f, -1e30f};
  float l[2] = {0.f, 0.f};

  Frags F;
  for (int t = 0; t < c; ++t) {
    load_frags(F, t << 5, r16, g4, Kp, Vp);
    compute_tile<0>(F, r16, g4, qf[0], o[0], m[0], l[0]);
    compute_tile<0>(F, r16, g4, qf[1], o[1], m[1], l[1]);
  }
  load_frags(F, c << 5, r16, g4, Kp, Vp);
  compute_tile<2>(F, r16, g4, qf[0], o[0], m[0], l[0]);
  compute_tile<1>(F, r16, g4, qf[1], o[1], m[1], l[1]);

#pragma unroll
  for (int ss = 0; ss < 2; ++ss) {
    float inv = 1.0f / l[ss];
    unsigned short* yrow = Y + ((size_t)(b * TT + Q0 + ss * 16 + r16) * CCH) + h * 64;
#pragma unroll
    for (int dblk = 0; dblk < 4; ++dblk) {
      float v0 = o[ss][dblk][0] * inv, v1 = o[ss][dblk][1] * inv;
      float v2 = o[ss][dblk][2] * inv, v3 = o[ss][dblk][3] * inv;
      int wa, wb;
      CVTPK(wa, v0, v1);
      CVTPK(wb, v2, v3);
      int2 pk; pk.x = wa; pk.y = wb;
      *reinterpret_cast<int2*>(&yrow[dblk * 16 + g4 * 4]) = pk;
    }
  }
}

__global__ __launch_bounds__(64, 2) void attn_kernel(const unsigned short* __restrict__ Qm,
                                                     const unsigned short* __restrict__ Km,
                                                     const unsigned short* __restrict__ Vt,
                                                     unsigned short* __restrict__ Y) {
  int lane = threadIdx.x;
  int r16 = lane & 15, g4 = lane >> 4;
  int bh = blockIdx.y;
  int c = blockIdx.x;                     // pair {c, 63-c}: 65 tiles per wave
  const unsigned short* Qp = Qm + (size_t)bh * TT * HSS;
  const unsigned short* Kp = Km + (size_t)bh * TT * HSS;
  const unsigned short* Vp = Vt + (size_t)bh * HSS * TT;
  int b = bh >> 4, h = bh & 15;

  do_chunk(63 - c, r16, g4, Qp, Kp, Vp, Y, b, h);  // heavy chunk first
  do_chunk(c, r16, g4, Qp, Kp, Vp, Y, b, h);
}

// ---------------- host ----------------
extern "C" void kernel_launch(void* const* d_in, const int* in_sizes, int n_in,
                              void* d_out, int out_size, void* d_ws, size_t ws_size,
                              hipStream_t stream) {
  const float* x      = (const float*)d_in[0];
  const float* w_attn = (const float*)d_in[1];
  const float* b_attn = (const float*)d_in[2];
  const float* w_proj = (const float*)d_in[3];
  const float* b_proj = (const float*)d_in[4];
  float* out = (float*)d_out;

  char* ws = (char*)d_ws;
  unsigned short* xb  = (unsigned short*)(ws + 0);          // 8192x1024 bf16; reused as Y
  unsigned short* wta = (unsigned short*)(ws + 16777216);   // 3072x1024 bf16
  unsigned short* wtp = (unsigned short*)(ws + 23068672);   // 1024x1024 bf16
  unsigned short* qb  = (unsigned short*)(ws + 25165824);   // q,k: [64][2048][64]; vt: [64][64][2048]
  unsigned short* yb  = xb;

  cast_f32_bf16<<<(MROWS * CCH) / 1024, 256, 0, stream>>>(x, xb, MROWS * CCH);
  transpose_cast<<<(CCH * 3 * CCH + 255) / 256, 256, 0, stream>>>(w_attn, wta, CCH, 3 * CCH);
  transpose_cast<<<(CCH * CCH + 255) / 256, 256, 0, stream>>>(w_proj, wtp, CCH, CCH);

  {
    dim3 grid(3 * CCH / 128, MROWS / 128);
    gemm_bt<1><<<grid, 256, 0, stream>>>(xb, wta, b_attn, nullptr, qb, MROWS, 3 * CCH, CCH);
  }
  {
    dim3 grid(32, BB * NHH);   // 32 chunk-pairs x 64 bh, 1 wave each
    attn_kernel<<<grid, 64, 0, stream>>>(qb, qb + (size_t)QKV_ELEMS, qb + 2 * (size_t)QKV_ELEMS, yb);
  }
  {
    dim3 grid(CCH / 128, MROWS / 128);
    gemm_bt<0><<<grid, 256, 0, stream>>>(yb, wtp, b_proj, out, nullptr, MROWS, CCH, CCH);
  }
}

// Round 11
// 330.171 us; speedup vs baseline: 1.0603x; 1.0603x over previous
//
#include <hip/hip_runtime.h>
#include <hip/hip_bf16.h>

// Problem constants
#define BB 4
#define TT 2048
#define CCH 1024
#define NHH 16
#define HSS 64
#define MROWS (BB * TT)            // 8192
#define QKV_ELEMS (64 * 2048 * 64) // per-tensor elems = 8388608

typedef __attribute__((ext_vector_type(8))) short short8;
typedef __attribute__((ext_vector_type(4))) float f32x4;

#define CVTPK(d, a, b) asm("v_cvt_pk_bf16_f32 %0, %1, %2" : "=v"(d) : "v"(a), "v"(b))

static __device__ __forceinline__ unsigned short bf16_of(float f) {
  union { float f; unsigned u; } v; v.f = f;
  unsigned u = v.u;
  return (unsigned short)((u + 0x7FFFu + ((u >> 16) & 1u)) >> 16);
}

// ---------------- cast kernels ----------------
__global__ __launch_bounds__(256) void cast_f32_bf16(const float* __restrict__ in,
                                                     unsigned short* __restrict__ out, int n) {
  int i = (blockIdx.x * 256 + threadIdx.x) * 4;
  if (i < n) {
    float4 f = *reinterpret_cast<const float4*>(in + i);
    ushort4 o;
    o.x = bf16_of(f.x); o.y = bf16_of(f.y); o.z = bf16_of(f.z); o.w = bf16_of(f.w);
    *reinterpret_cast<ushort4*>(out + i) = o;
  }
}

// in: [K][N] f32 row-major -> out: [N][K] bf16 row-major
__global__ __launch_bounds__(256) void transpose_cast(const float* __restrict__ in,
                                                      unsigned short* __restrict__ out,
                                                      int K, int N) {
  int idx = blockIdx.x * 256 + threadIdx.x;
  if (idx < K * N) {
    int k = idx / N;
    int n = idx - k * N;
    out[(size_t)n * K + k] = bf16_of(in[idx]);
  }
}

// ---------------- GEMM: C = A[M,K] @ Bt[N,K]^T + bias (verified R1-R3) ----------------
template <int MODE>
__global__ __launch_bounds__(256) void gemm_bt(const unsigned short* __restrict__ A,
                                               const unsigned short* __restrict__ Bt,
                                               const float* __restrict__ bias,
                                               float* __restrict__ outF,
                                               unsigned short* __restrict__ outQKV,
                                               int M, int N, int K) {
  __shared__ unsigned short As[128 * 32];
  __shared__ unsigned short Bs[128 * 32];
  int tid = threadIdx.x;
  int w = tid >> 6, lane = tid & 63;
  int g = lane >> 4, r16 = lane & 15;
  int wr = w >> 1, wc = w & 1;
  int m0 = blockIdx.y * 128, n0 = blockIdx.x * 128;
  int lrow = lane >> 2;
  int lcol = (lane & 3) * 8;

  f32x4 zero = {0.f, 0.f, 0.f, 0.f};
  f32x4 acc[4][4];
#pragma unroll
  for (int i = 0; i < 4; ++i)
#pragma unroll
    for (int n = 0; n < 4; ++n) acc[i][n] = zero;

  for (int kt = 0; kt < K; kt += 32) {
#pragma unroll
    for (int c = 0; c < 2; ++c) {
      int rg = w * 32 + c * 16;
      __builtin_amdgcn_global_load_lds(
          (const __attribute__((address_space(1))) void*)(&A[(size_t)(m0 + rg + lrow) * K + kt + lcol]),
          (__attribute__((address_space(3))) void*)(&As[rg * 32]), 16, 0, 0);
      __builtin_amdgcn_global_load_lds(
          (const __attribute__((address_space(1))) void*)(&Bt[(size_t)(n0 + rg + lrow) * K + kt + lcol]),
          (__attribute__((address_space(3))) void*)(&Bs[rg * 32]), 16, 0, 0);
    }
    __syncthreads();
    short8 af[4], bfr[4];
#pragma unroll
    for (int i = 0; i < 4; ++i)
      af[i] = *reinterpret_cast<const short8*>(&As[(wr * 64 + i * 16 + r16) * 32 + g * 8]);
#pragma unroll
    for (int i = 0; i < 4; ++i)
      bfr[i] = *reinterpret_cast<const short8*>(&Bs[(wc * 64 + i * 16 + r16) * 32 + g * 8]);
#pragma unroll
    for (int i = 0; i < 4; ++i)
#pragma unroll
      for (int n = 0; n < 4; ++n)
        acc[i][n] = __builtin_amdgcn_mfma_f32_16x16x32_bf16(af[i], bfr[n], acc[i][n], 0, 0, 0);
    __syncthreads();
  }

#pragma unroll
  for (int i = 0; i < 4; ++i)
#pragma unroll
    for (int n = 0; n < 4; ++n)
#pragma unroll
      for (int j = 0; j < 4; ++j) {
        int row = m0 + wr * 64 + i * 16 + g * 4 + j;
        int col = n0 + wc * 64 + n * 16 + r16;
        float val = acc[i][n][j] + bias[col];
        if (MODE == 0) {
          outF[(size_t)row * N + col] = val;
        } else {
          int which = col >> 10, c = col & 1023;
          int h = c >> 6, d = c & 63;
          int b = row >> 11, t = row & 2047;
          if (which == 2) {
            outQKV[2 * (size_t)QKV_ELEMS +
                   (((size_t)(b * 16 + h) * 64 + d) * 2048 + t)] = bf16_of(val);
          } else {
            if (which == 0) val *= 0.125f;   // fold 1/sqrt(HS) into Q (exact pow2)
            outQKV[(size_t)which * QKV_ELEMS +
                   (((size_t)(b * 16 + h) * 2048 + t) * 64 + d)] = bf16_of(val);
          }
        }
      }
}

// ---------------- causal flash attention ----------------
// R8 structure verbatim (64-row q-block/wave, 4-strip reuse, heavy-first,
// single Frags, no dbuf) + R9's shuffle-free PV verbatim (sigma-permuted V,
// own-lane P fragments, unconditional rescale). No defer-max.
struct Frags {
  short8 kf0[2], kf1[2];
  union VU { int w[4]; short8 s8; } vf[4];
};

static __device__ __forceinline__ void load_frags(Frags& f, int key0, int r16, int g4,
                                                  const unsigned short* __restrict__ Kp,
                                                  const unsigned short* __restrict__ Vp) {
#pragma unroll
  for (int c = 0; c < 2; ++c)
    f.kf0[c] = *reinterpret_cast<const short8*>(&Kp[(size_t)(key0 + r16) * 64 + c * 32 + g4 * 8]);
#pragma unroll
  for (int c = 0; c < 2; ++c)
    f.kf1[c] = *reinterpret_cast<const short8*>(&Kp[(size_t)(key0 + 16 + r16) * 64 + c * 32 + g4 * 8]);
#pragma unroll
  for (int dblk = 0; dblk < 4; ++dblk) {
    const unsigned short* vrow = &Vp[(size_t)(dblk * 16 + r16) * TT + key0 + 4 * g4];
    int2 lo = *reinterpret_cast<const int2*>(vrow);        // keys key0+4g4+{0..3}
    int2 hi = *reinterpret_cast<const int2*>(vrow + 16);   // keys key0+16+4g4+{0..3}
    f.vf[dblk].w[0] = lo.x; f.vf[dblk].w[1] = lo.y;
    f.vf[dblk].w[2] = hi.x; f.vf[dblk].w[3] = hi.y;
  }
}

// MODE 0: full 32-key tile. MODE 1: kb0 full + kb1 diag. MODE 2: kb0 diag only.
template <int MODE>
static __device__ __forceinline__ void compute_tile(const Frags& f, int r16, int g4,
                                                    const short8 qf[2], f32x4 o[4],
                                                    float& m, float& lsum) {
  f32x4 zero = {0.f, 0.f, 0.f, 0.f};
  f32x4 s0 = zero, s1 = zero;
  __builtin_amdgcn_s_setprio(1);
  s0 = __builtin_amdgcn_mfma_f32_16x16x32_bf16(f.kf0[0], qf[0], s0, 0, 0, 0);
  s0 = __builtin_amdgcn_mfma_f32_16x16x32_bf16(f.kf0[1], qf[1], s0, 0, 0, 0);
  if (MODE != 2) {
    s1 = __builtin_amdgcn_mfma_f32_16x16x32_bf16(f.kf1[0], qf[0], s1, 0, 0, 0);
    s1 = __builtin_amdgcn_mfma_f32_16x16x32_bf16(f.kf1[1], qf[1], s1, 0, 0, 0);
  }
  __builtin_amdgcn_s_setprio(0);

  if (MODE == 2) {
#pragma unroll
    for (int r = 0; r < 4; ++r)
      if (g4 * 4 + r > r16) s0[r] = -1e30f;
  }
  if (MODE == 1) {
#pragma unroll
    for (int r = 0; r < 4; ++r)
      if (g4 * 4 + r > r16) s1[r] = -1e30f;
  }

  float om = fmaxf(fmaxf(s0[0], s0[1]), fmaxf(s0[2], s0[3]));
  if (MODE != 2)
    om = fmaxf(om, fmaxf(fmaxf(s1[0], s1[1]), fmaxf(s1[2], s1[3])));
  om = fmaxf(om, __shfl_xor(om, 16));
  om = fmaxf(om, __shfl_xor(om, 32));
  float mn = fmaxf(m, om);
  float alpha = __expf(m - mn);
  m = mn;

  float p0[4], p1[4];
#pragma unroll
  for (int r = 0; r < 4; ++r) {
    p0[r] = __expf(s0[r] - mn);
    if (MODE != 2) p1[r] = __expf(s1[r] - mn);
  }
  float rs = (p0[0] + p0[1]) + (p0[2] + p0[3]);
  if (MODE != 2) rs += (p1[0] + p1[1]) + (p1[2] + p1[3]);
  rs += __shfl_xor(rs, 16);
  rs += __shfl_xor(rs, 32);
  lsum = lsum * alpha + rs;
#pragma unroll
  for (int dblk = 0; dblk < 4; ++dblk)
#pragma unroll
    for (int r = 0; r < 4; ++r) o[dblk][r] *= alpha;

  // P B-fragment from the lane's OWN values (sigma-permuted key order)
  union { int w[4]; short8 s8; } pf;
  CVTPK(pf.w[0], p0[0], p0[1]);
  CVTPK(pf.w[1], p0[2], p0[3]);
  if (MODE != 2) {
    CVTPK(pf.w[2], p1[0], p1[1]);
    CVTPK(pf.w[3], p1[2], p1[3]);
  } else {
    pf.w[2] = 0; pf.w[3] = 0;
  }

  __builtin_amdgcn_s_setprio(1);
#pragma unroll
  for (int dblk = 0; dblk < 4; ++dblk)
    o[dblk] = __builtin_amdgcn_mfma_f32_16x16x32_bf16(f.vf[dblk].s8, pf.s8, o[dblk], 0, 0, 0);
  __builtin_amdgcn_s_setprio(0);
}

__global__ __launch_bounds__(64, 2) void attn_kernel(const unsigned short* __restrict__ Qm,
                                                     const unsigned short* __restrict__ Km,
                                                     const unsigned short* __restrict__ Vt,
                                                     unsigned short* __restrict__ Y) {
  int lane = threadIdx.x;
  int r16 = lane & 15, g4 = lane >> 4;
  int bh = blockIdx.y;
  int a = (int)(gridDim.x - 1 - blockIdx.x); // heavy-first
  int Q0 = a * 64;
  const unsigned short* Qp = Qm + (size_t)bh * TT * HSS;
  const unsigned short* Kp = Km + (size_t)bh * TT * HSS;
  const unsigned short* Vp = Vt + (size_t)bh * HSS * TT;

  // Q fragments for 4 strips (rows Q0+16ss+r16)
  short8 qf[4][2];
#pragma unroll
  for (int ss = 0; ss < 4; ++ss)
#pragma unroll
    for (int c = 0; c < 2; ++c)
      qf[ss][c] = *reinterpret_cast<const short8*>(
          &Qp[(size_t)(Q0 + ss * 16 + r16) * 64 + c * 32 + g4 * 8]);

  f32x4 o[4][4];
#pragma unroll
  for (int ss = 0; ss < 4; ++ss)
#pragma unroll
    for (int dblk = 0; dblk < 4; ++dblk) o[ss][dblk] = f32x4{0.f, 0.f, 0.f, 0.f};
  float m[4] = {-1e30f, -1e30f, -1e30f, -1e30f};
  float l[4] = {0.f, 0.f, 0.f, 0.f};

  Frags F;
  // tiles full for all 4 strips: t = 0 .. 2a-1
  int nfull = a * 2;
  for (int t = 0; t < nfull; ++t) {
    load_frags(F, t << 5, r16, g4, Kp, Vp);
#pragma unroll
    for (int ss = 0; ss < 4; ++ss)
      compute_tile<0>(F, r16, g4, qf[ss], o[ss], m[ss], l[ss]);
  }
  // tile 2a (key0 = Q0): ss0 diag(M2), ss1 M1, ss2/ss3 full
  load_frags(F, Q0, r16, g4, Kp, Vp);
  compute_tile<2>(F, r16, g4, qf[0], o[0], m[0], l[0]);
  compute_tile<1>(F, r16, g4, qf[1], o[1], m[1], l[1]);
  compute_tile<0>(F, r16, g4, qf[2], o[2], m[2], l[2]);
  compute_tile<0>(F, r16, g4, qf[3], o[3], m[3], l[3]);
  // tile 2a+1 (key0 = Q0+32): ss2 M2, ss3 M1
  load_frags(F, Q0 + 32, r16, g4, Kp, Vp);
  compute_tile<2>(F, r16, g4, qf[2], o[2], m[2], l[2]);
  compute_tile<1>(F, r16, g4, qf[3], o[3], m[3], l[3]);

  // epilogue
  int b = bh >> 4, h = bh & 15;
#pragma unroll
  for (int ss = 0; ss < 4; ++ss) {
    float inv = 1.0f / l[ss];
    unsigned short* yrow = Y + ((size_t)(b * TT + Q0 + ss * 16 + r16) * CCH) + h * 64;
#pragma unroll
    for (int dblk = 0; dblk < 4; ++dblk) {
      float v0 = o[ss][dblk][0] * inv, v1 = o[ss][dblk][1] * inv;
      float v2 = o[ss][dblk][2] * inv, v3 = o[ss][dblk][3] * inv;
      int wa, wb;
      CVTPK(wa, v0, v1);
      CVTPK(wb, v2, v3);
      int2 pk; pk.x = wa; pk.y = wb;
      *reinterpret_cast<int2*>(&yrow[dblk * 16 + g4 * 4]) = pk;
    }
  }
}

// ---------------- host ----------------
extern "C" void kernel_launch(void* const* d_in, const int* in_sizes, int n_in,
                              void* d_out, int out_size, void* d_ws, size_t ws_size,
                              hipStream_t stream) {
  const float* x      = (const float*)d_in[0];
  const float* w_attn = (const float*)d_in[1];
  const float* b_attn = (const float*)d_in[2];
  const float* w_proj = (const float*)d_in[3];
  const float* b_proj = (const float*)d_in[4];
  float* out = (float*)d_out;

  char* ws = (char*)d_ws;
  unsigned short* xb  = (unsigned short*)(ws + 0);          // 8192x1024 bf16; reused as Y
  unsigned short* wta = (unsigned short*)(ws + 16777216);   // 3072x1024 bf16
  unsigned short* wtp = (unsigned short*)(ws + 23068672);   // 1024x1024 bf16
  unsigned short* qb  = (unsigned short*)(ws + 25165824);   // q,k: [64][2048][64]; vt: [64][64][2048]
  unsigned short* yb  = xb;

  cast_f32_bf16<<<(MROWS * CCH) / 1024, 256, 0, stream>>>(x, xb, MROWS * CCH);
  transpose_cast<<<(CCH * 3 * CCH + 255) / 256, 256, 0, stream>>>(w_attn, wta, CCH, 3 * CCH);
  transpose_cast<<<(CCH * CCH + 255) / 256, 256, 0, stream>>>(w_proj, wtp, CCH, CCH);

  {
    dim3 grid(3 * CCH / 128, MROWS / 128);
    gemm_bt<1><<<grid, 256, 0, stream>>>(xb, wta, b_attn, nullptr, qb, MROWS, 3 * CCH, CCH);
  }
  {
    dim3 grid(TT / 64, BB * NHH);   // 32 q-blocks x 64 bh, 1 wave each
    attn_kernel<<<grid, 64, 0, stream>>>(qb, qb + (size_t)QKV_ELEMS, qb + 2 * (size_t)QKV_ELEMS, yb);
  }
  {
    dim3 grid(CCH / 128, MROWS / 128);
    gemm_bt<0><<<grid, 256, 0, stream>>>(yb, wtp, b_proj, out, nullptr, MROWS, CCH, CCH);
  }
}

// Round 12
// 283.900 us; speedup vs baseline: 1.2331x; 1.1630x over previous
//
#include <hip/hip_runtime.h>
#include <hip/hip_bf16.h>

// Problem constants
#define BB 4
#define TT 2048
#define CCH 1024
#define NHH 16
#define HSS 64
#define MROWS (BB * TT)            // 8192
#define QKV_ELEMS (64 * 2048 * 64) // per-tensor elems = 8388608

typedef __attribute__((ext_vector_type(8))) short short8;
typedef __attribute__((ext_vector_type(4))) float f32x4;

#define CVTPK(d, a, b) asm("v_cvt_pk_bf16_f32 %0, %1, %2" : "=v"(d) : "v"(a), "v"(b))

static __device__ __forceinline__ unsigned short bf16_of(float f) {
  union { float f; unsigned u; } v; v.f = f;
  unsigned u = v.u;
  return (unsigned short)((u + 0x7FFFu + ((u >> 16) & 1u)) >> 16);
}

// ---------------- cast kernels ----------------
__global__ __launch_bounds__(256) void cast_f32_bf16(const float* __restrict__ in,
                                                     unsigned short* __restrict__ out, int n) {
  int i = (blockIdx.x * 256 + threadIdx.x) * 4;
  if (i < n) {
    float4 f = *reinterpret_cast<const float4*>(in + i);
    ushort4 o;
    o.x = bf16_of(f.x); o.y = bf16_of(f.y); o.z = bf16_of(f.z); o.w = bf16_of(f.w);
    *reinterpret_cast<ushort4*>(out + i) = o;
  }
}

// in: [K][N] f32 row-major -> out: [N][K] bf16 row-major
__global__ __launch_bounds__(256) void transpose_cast(const float* __restrict__ in,
                                                      unsigned short* __restrict__ out,
                                                      int K, int N) {
  int idx = blockIdx.x * 256 + threadIdx.x;
  if (idx < K * N) {
    int k = idx / N;
    int n = idx - k * N;
    out[(size_t)n * K + k] = bf16_of(in[idx]);
  }
}

// ---------------- GEMM: C = A[M,K] @ Bt[N,K]^T + bias (verified R1-R3) ----------------
// MODE 1 epilogue: q (pre-scaled), k in [B*NH][T][HS]; v transposed -> [B*NH][HS][T]
// with keys sigma-PERMUTED within each 32-key block so the attn PV A-fragment
// is one contiguous 16B load AND the B-fragment is the lane's own p-values.
template <int MODE>
__global__ __launch_bounds__(256) void gemm_bt(const unsigned short* __restrict__ A,
                                               const unsigned short* __restrict__ Bt,
                                               const float* __restrict__ bias,
                                               float* __restrict__ outF,
                                               unsigned short* __restrict__ outQKV,
                                               int M, int N, int K) {
  __shared__ unsigned short As[128 * 32];
  __shared__ unsigned short Bs[128 * 32];
  int tid = threadIdx.x;
  int w = tid >> 6, lane = tid & 63;
  int g = lane >> 4, r16 = lane & 15;
  int wr = w >> 1, wc = w & 1;
  int m0 = blockIdx.y * 128, n0 = blockIdx.x * 128;
  int lrow = lane >> 2;
  int lcol = (lane & 3) * 8;

  f32x4 zero = {0.f, 0.f, 0.f, 0.f};
  f32x4 acc[4][4];
#pragma unroll
  for (int i = 0; i < 4; ++i)
#pragma unroll
    for (int n = 0; n < 4; ++n) acc[i][n] = zero;

  for (int kt = 0; kt < K; kt += 32) {
#pragma unroll
    for (int c = 0; c < 2; ++c) {
      int rg = w * 32 + c * 16;
      __builtin_amdgcn_global_load_lds(
          (const __attribute__((address_space(1))) void*)(&A[(size_t)(m0 + rg + lrow) * K + kt + lcol]),
          (__attribute__((address_space(3))) void*)(&As[rg * 32]), 16, 0, 0);
      __builtin_amdgcn_global_load_lds(
          (const __attribute__((address_space(1))) void*)(&Bt[(size_t)(n0 + rg + lrow) * K + kt + lcol]),
          (__attribute__((address_space(3))) void*)(&Bs[rg * 32]), 16, 0, 0);
    }
    __syncthreads();
    short8 af[4], bfr[4];
#pragma unroll
    for (int i = 0; i < 4; ++i)
      af[i] = *reinterpret_cast<const short8*>(&As[(wr * 64 + i * 16 + r16) * 32 + g * 8]);
#pragma unroll
    for (int i = 0; i < 4; ++i)
      bfr[i] = *reinterpret_cast<const short8*>(&Bs[(wc * 64 + i * 16 + r16) * 32 + g * 8]);
#pragma unroll
    for (int i = 0; i < 4; ++i)
#pragma unroll
      for (int n = 0; n < 4; ++n)
        acc[i][n] = __builtin_amdgcn_mfma_f32_16x16x32_bf16(af[i], bfr[n], acc[i][n], 0, 0, 0);
    __syncthreads();
  }

#pragma unroll
  for (int i = 0; i < 4; ++i)
#pragma unroll
    for (int n = 0; n < 4; ++n)
#pragma unroll
      for (int j = 0; j < 4; ++j) {
        int row = m0 + wr * 64 + i * 16 + g * 4 + j;
        int col = n0 + wc * 64 + n * 16 + r16;
        float val = acc[i][n][j] + bias[col];
        if (MODE == 0) {
          outF[(size_t)row * N + col] = val;
        } else {
          int which = col >> 10, c = col & 1023;
          int h = c >> 6, d = c & 63;
          int b = row >> 11, t = row & 2047;
          if (which == 2) {
            // sigma-permute key index within its 32-block:
            // p(k) = (k<16) ? (k>>2)*8+(k&3) : ((k-16)>>2)*8+4+((k-16)&3)
            int k5 = t & 31;
            int p = (k5 < 16) ? ((k5 >> 2) * 8 + (k5 & 3))
                              : (((k5 - 16) >> 2) * 8 + 4 + ((k5 - 16) & 3));
            int tp = (t & ~31) | p;
            outQKV[2 * (size_t)QKV_ELEMS +
                   (((size_t)(b * 16 + h) * 64 + d) * 2048 + tp)] = bf16_of(val);
          } else {
            if (which == 0) val *= 0.125f;   // fold 1/sqrt(HS) into Q (exact pow2)
            outQKV[(size_t)which * QKV_ELEMS +
                   (((size_t)(b * 16 + h) * 2048 + t) * 64 + d)] = bf16_of(val);
          }
        }
      }
}

// ---------------- causal flash attention ----------------
// R8 structure verbatim (64-row q-block/wave, 4-strip reuse, heavy-first,
// single Frags) + R11's own-lane P fragments + 16B V loads from the
// sigma-permuted V^T layout. Zero crossbar ops in the P path.
struct Frags {
  short8 kf0[2], kf1[2], vf[4];
};

static __device__ __forceinline__ void load_frags(Frags& f, int key0, int r16, int g4,
                                                  const unsigned short* __restrict__ Kp,
                                                  const unsigned short* __restrict__ Vp) {
#pragma unroll
  for (int c = 0; c < 2; ++c)
    f.kf0[c] = *reinterpret_cast<const short8*>(&Kp[(size_t)(key0 + r16) * 64 + c * 32 + g4 * 8]);
#pragma unroll
  for (int c = 0; c < 2; ++c)
    f.kf1[c] = *reinterpret_cast<const short8*>(&Kp[(size_t)(key0 + 16 + r16) * 64 + c * 32 + g4 * 8]);
#pragma unroll
  for (int dblk = 0; dblk < 4; ++dblk)
    f.vf[dblk] = *reinterpret_cast<const short8*>(
        &Vp[(size_t)(dblk * 16 + r16) * TT + key0 + g4 * 8]);  // positions g4*8..+7 (sigma order)
}

// MODE 0: full 32-key tile. MODE 1: kb0 full + kb1 diag. MODE 2: kb0 diag only.
template <int MODE>
static __device__ __forceinline__ void compute_tile(const Frags& f, int r16, int g4,
                                                    const short8 qf[2], f32x4 o[4],
                                                    float& m, float& lsum) {
  f32x4 zero = {0.f, 0.f, 0.f, 0.f};
  f32x4 s0 = zero, s1 = zero;
  __builtin_amdgcn_s_setprio(1);
  s0 = __builtin_amdgcn_mfma_f32_16x16x32_bf16(f.kf0[0], qf[0], s0, 0, 0, 0);
  s0 = __builtin_amdgcn_mfma_f32_16x16x32_bf16(f.kf0[1], qf[1], s0, 0, 0, 0);
  if (MODE != 2) {
    s1 = __builtin_amdgcn_mfma_f32_16x16x32_bf16(f.kf1[0], qf[0], s1, 0, 0, 0);
    s1 = __builtin_amdgcn_mfma_f32_16x16x32_bf16(f.kf1[1], qf[1], s1, 0, 0, 0);
  }
  __builtin_amdgcn_s_setprio(0);

  if (MODE == 2) {
#pragma unroll
    for (int r = 0; r < 4; ++r)
      if (g4 * 4 + r > r16) s0[r] = -1e30f;
  }
  if (MODE == 1) {
#pragma unroll
    for (int r = 0; r < 4; ++r)
      if (g4 * 4 + r > r16) s1[r] = -1e30f;
  }

  float om = fmaxf(fmaxf(s0[0], s0[1]), fmaxf(s0[2], s0[3]));
  if (MODE != 2)
    om = fmaxf(om, fmaxf(fmaxf(s1[0], s1[1]), fmaxf(s1[2], s1[3])));
  om = fmaxf(om, __shfl_xor(om, 16));
  om = fmaxf(om, __shfl_xor(om, 32));
  float mn = fmaxf(m, om);
  float alpha = __expf(m - mn);
  m = mn;

  float p0[4], p1[4];
#pragma unroll
  for (int r = 0; r < 4; ++r) {
    p0[r] = __expf(s0[r] - mn);
    if (MODE != 2) p1[r] = __expf(s1[r] - mn);
  }
  float rs = (p0[0] + p0[1]) + (p0[2] + p0[3]);
  if (MODE != 2) rs += (p1[0] + p1[1]) + (p1[2] + p1[3]);
  rs += __shfl_xor(rs, 16);
  rs += __shfl_xor(rs, 32);
  lsum = lsum * alpha + rs;
#pragma unroll
  for (int dblk = 0; dblk < 4; ++dblk)
#pragma unroll
    for (int r = 0; r < 4; ++r) o[dblk][r] *= alpha;

  // P B-fragment from the lane's OWN values (sigma key order, matches V layout)
  union { int w[4]; short8 s8; } pf;
  CVTPK(pf.w[0], p0[0], p0[1]);
  CVTPK(pf.w[1], p0[2], p0[3]);
  if (MODE != 2) {
    CVTPK(pf.w[2], p1[0], p1[1]);
    CVTPK(pf.w[3], p1[2], p1[3]);
  } else {
    pf.w[2] = 0; pf.w[3] = 0;
  }

  __builtin_amdgcn_s_setprio(1);
#pragma unroll
  for (int dblk = 0; dblk < 4; ++dblk)
    o[dblk] = __builtin_amdgcn_mfma_f32_16x16x32_bf16(f.vf[dblk], pf.s8, o[dblk], 0, 0, 0);
  __builtin_amdgcn_s_setprio(0);
}

__global__ __launch_bounds__(64, 2) void attn_kernel(const unsigned short* __restrict__ Qm,
                                                     const unsigned short* __restrict__ Km,
                                                     const unsigned short* __restrict__ Vt,
                                                     unsigned short* __restrict__ Y) {
  int lane = threadIdx.x;
  int r16 = lane & 15, g4 = lane >> 4;
  int bh = blockIdx.y;
  int a = (int)(gridDim.x - 1 - blockIdx.x); // heavy-first
  int Q0 = a * 64;
  const unsigned short* Qp = Qm + (size_t)bh * TT * HSS;
  const unsigned short* Kp = Km + (size_t)bh * TT * HSS;
  const unsigned short* Vp = Vt + (size_t)bh * HSS * TT;

  // Q fragments for 4 strips (rows Q0+16ss+r16)
  short8 qf[4][2];
#pragma unroll
  for (int ss = 0; ss < 4; ++ss)
#pragma unroll
    for (int c = 0; c < 2; ++c)
      qf[ss][c] = *reinterpret_cast<const short8*>(
          &Qp[(size_t)(Q0 + ss * 16 + r16) * 64 + c * 32 + g4 * 8]);

  f32x4 o[4][4];
#pragma unroll
  for (int ss = 0; ss < 4; ++ss)
#pragma unroll
    for (int dblk = 0; dblk < 4; ++dblk) o[ss][dblk] = f32x4{0.f, 0.f, 0.f, 0.f};
  float m[4] = {-1e30f, -1e30f, -1e30f, -1e30f};
  float l[4] = {0.f, 0.f, 0.f, 0.f};

  Frags F;
  // tiles full for all 4 strips: t = 0 .. 2a-1
  int nfull = a * 2;
  for (int t = 0; t < nfull; ++t) {
    load_frags(F, t << 5, r16, g4, Kp, Vp);
#pragma unroll
    for (int ss = 0; ss < 4; ++ss)
      compute_tile<0>(F, r16, g4, qf[ss], o[ss], m[ss], l[ss]);
  }
  // tile 2a (key0 = Q0): ss0 diag(M2), ss1 M1, ss2/ss3 full
  load_frags(F, Q0, r16, g4, Kp, Vp);
  compute_tile<2>(F, r16, g4, qf[0], o[0], m[0], l[0]);
  compute_tile<1>(F, r16, g4, qf[1], o[1], m[1], l[1]);
  compute_tile<0>(F, r16, g4, qf[2], o[2], m[2], l[2]);
  compute_tile<0>(F, r16, g4, qf[3], o[3], m[3], l[3]);
  // tile 2a+1 (key0 = Q0+32): ss2 M2, ss3 M1
  load_frags(F, Q0 + 32, r16, g4, Kp, Vp);
  compute_tile<2>(F, r16, g4, qf[2], o[2], m[2], l[2]);
  compute_tile<1>(F, r16, g4, qf[3], o[3], m[3], l[3]);

  // epilogue
  int b = bh >> 4, h = bh & 15;
#pragma unroll
  for (int ss = 0; ss < 4; ++ss) {
    float inv = 1.0f / l[ss];
    unsigned short* yrow = Y + ((size_t)(b * TT + Q0 + ss * 16 + r16) * CCH) + h * 64;
#pragma unroll
    for (int dblk = 0; dblk < 4; ++dblk) {
      float v0 = o[ss][dblk][0] * inv, v1 = o[ss][dblk][1] * inv;
      float v2 = o[ss][dblk][2] * inv, v3 = o[ss][dblk][3] * inv;
      int wa, wb;
      CVTPK(wa, v0, v1);
      CVTPK(wb, v2, v3);
      int2 pk; pk.x = wa; pk.y = wb;
      *reinterpret_cast<int2*>(&yrow[dblk * 16 + g4 * 4]) = pk;
    }
  }
}

// ---------------- host ----------------
extern "C" void kernel_launch(void* const* d_in, const int* in_sizes, int n_in,
                              void* d_out, int out_size, void* d_ws, size_t ws_size,
                              hipStream_t stream) {
  const float* x      = (const float*)d_in[0];
  const float* w_attn = (const float*)d_in[1];
  const float* b_attn = (const float*)d_in[2];
  const float* w_proj = (const float*)d_in[3];
  const float* b_proj = (const float*)d_in[4];
  float* out = (float*)d_out;

  char* ws = (char*)d_ws;
  unsigned short* xb  = (unsigned short*)(ws + 0);          // 8192x1024 bf16; reused as Y
  unsigned short* wta = (unsigned short*)(ws + 16777216);   // 3072x1024 bf16
  unsigned short* wtp = (unsigned short*)(ws + 23068672);   // 1024x1024 bf16
  unsigned short* qb  = (unsigned short*)(ws + 25165824);   // q,k: [64][2048][64]; vt(sigma): [64][64][2048]
  unsigned short* yb  = xb;

  cast_f32_bf16<<<(MROWS * CCH) / 1024, 256, 0, stream>>>(x, xb, MROWS * CCH);
  transpose_cast<<<(CCH * 3 * CCH + 255) / 256, 256, 0, stream>>>(w_attn, wta, CCH, 3 * CCH);
  transpose_cast<<<(CCH * CCH + 255) / 256, 256, 0, stream>>>(w_proj, wtp, CCH, CCH);

  {
    dim3 grid(3 * CCH / 128, MROWS / 128);
    gemm_bt<1><<<grid, 256, 0, stream>>>(xb, wta, b_attn, nullptr, qb, MROWS, 3 * CCH, CCH);
  }
  {
    dim3 grid(TT / 64, BB * NHH);   // 32 q-blocks x 64 bh, 1 wave each
    attn_kernel<<<grid, 64, 0, stream>>>(qb, qb + (size_t)QKV_ELEMS, qb + 2 * (size_t)QKV_ELEMS, yb);
  }
  {
    dim3 grid(CCH / 128, MROWS / 128);
    gemm_bt<0><<<grid, 256, 0, stream>>>(yb, wtp, b_proj, out, nullptr, MROWS, CCH, CCH);
  }
}

// Round 13
// 283.099 us; speedup vs baseline: 1.2366x; 1.0028x over previous
//
#include <hip/hip_runtime.h>
#include <hip/hip_bf16.h>

// Problem constants
#define BB 4
#define TT 2048
#define CCH 1024
#define NHH 16
#define HSS 64
#define MROWS (BB * TT)            // 8192
#define QKV_ELEMS (64 * 2048 * 64) // per-tensor elems = 8388608

typedef __attribute__((ext_vector_type(8))) short short8;
typedef __attribute__((ext_vector_type(4))) float f32x4;

#define CVTPK(d, a, b) asm("v_cvt_pk_bf16_f32 %0, %1, %2" : "=v"(d) : "v"(a), "v"(b))

static __device__ __forceinline__ unsigned short bf16_of(float f) {
  union { float f; unsigned u; } v; v.f = f;
  unsigned u = v.u;
  return (unsigned short)((u + 0x7FFFu + ((u >> 16) & 1u)) >> 16);
}

// ---------------- cast kernels ----------------
__global__ __launch_bounds__(256) void cast_f32_bf16(const float* __restrict__ in,
                                                     unsigned short* __restrict__ out, int n) {
  int i = (blockIdx.x * 256 + threadIdx.x) * 4;
  if (i < n) {
    float4 f = *reinterpret_cast<const float4*>(in + i);
    ushort4 o;
    o.x = bf16_of(f.x); o.y = bf16_of(f.y); o.z = bf16_of(f.z); o.w = bf16_of(f.w);
    *reinterpret_cast<ushort4*>(out + i) = o;
  }
}

// in: [K][N] f32 row-major -> out: [N][K] bf16 row-major
__global__ __launch_bounds__(256) void transpose_cast(const float* __restrict__ in,
                                                      unsigned short* __restrict__ out,
                                                      int K, int N) {
  int idx = blockIdx.x * 256 + threadIdx.x;
  if (idx < K * N) {
    int k = idx / N;
    int n = idx - k * N;
    out[(size_t)n * K + k] = bf16_of(in[idx]);
  }
}

// ---------------- GEMM: C = A[M,K] @ Bt[N,K]^T + bias (verified R1-R3) ----------------
// + bijective XCD-aware block swizzle (T1): each XCD gets a contiguous tile range.
// MODE 1 epilogue: q (pre-scaled), k in [B*NH][T][HS]; v transposed -> [B*NH][HS][T]
// with keys sigma-permuted within each 32-key block (R12, verified).
template <int MODE>
__global__ __launch_bounds__(256) void gemm_bt(const unsigned short* __restrict__ A,
                                               const unsigned short* __restrict__ Bt,
                                               const float* __restrict__ bias,
                                               float* __restrict__ outF,
                                               unsigned short* __restrict__ outQKV,
                                               int M, int N, int K) {
  __shared__ unsigned short As[128 * 32];
  __shared__ unsigned short Bs[128 * 32];
  int tid = threadIdx.x;
  int w = tid >> 6, lane = tid & 63;
  int g = lane >> 4, r16 = lane & 15;
  int wr = w >> 1, wc = w & 1;

  // XCD swizzle: dispatch id -> contiguous per-XCD tile range (nwg % 8 == 0)
  int nwg = (int)(gridDim.x * gridDim.y);
  int id = (int)(blockIdx.y * gridDim.x + blockIdx.x);
  int cpx = nwg >> 3;
  int swz = (id & 7) * cpx + (id >> 3);
  int m0 = (swz / (int)gridDim.x) * 128;
  int n0 = (swz % (int)gridDim.x) * 128;

  int lrow = lane >> 2;
  int lcol = (lane & 3) * 8;

  f32x4 zero = {0.f, 0.f, 0.f, 0.f};
  f32x4 acc[4][4];
#pragma unroll
  for (int i = 0; i < 4; ++i)
#pragma unroll
    for (int n = 0; n < 4; ++n) acc[i][n] = zero;

  for (int kt = 0; kt < K; kt += 32) {
#pragma unroll
    for (int c = 0; c < 2; ++c) {
      int rg = w * 32 + c * 16;
      __builtin_amdgcn_global_load_lds(
          (const __attribute__((address_space(1))) void*)(&A[(size_t)(m0 + rg + lrow) * K + kt + lcol]),
          (__attribute__((address_space(3))) void*)(&As[rg * 32]), 16, 0, 0);
      __builtin_amdgcn_global_load_lds(
          (const __attribute__((address_space(1))) void*)(&Bt[(size_t)(n0 + rg + lrow) * K + kt + lcol]),
          (__attribute__((address_space(3))) void*)(&Bs[rg * 32]), 16, 0, 0);
    }
    __syncthreads();
    short8 af[4], bfr[4];
#pragma unroll
    for (int i = 0; i < 4; ++i)
      af[i] = *reinterpret_cast<const short8*>(&As[(wr * 64 + i * 16 + r16) * 32 + g * 8]);
#pragma unroll
    for (int i = 0; i < 4; ++i)
      bfr[i] = *reinterpret_cast<const short8*>(&Bs[(wc * 64 + i * 16 + r16) * 32 + g * 8]);
#pragma unroll
    for (int i = 0; i < 4; ++i)
#pragma unroll
      for (int n = 0; n < 4; ++n)
        acc[i][n] = __builtin_amdgcn_mfma_f32_16x16x32_bf16(af[i], bfr[n], acc[i][n], 0, 0, 0);
    __syncthreads();
  }

#pragma unroll
  for (int i = 0; i < 4; ++i)
#pragma unroll
    for (int n = 0; n < 4; ++n)
#pragma unroll
      for (int j = 0; j < 4; ++j) {
        int row = m0 + wr * 64 + i * 16 + g * 4 + j;
        int col = n0 + wc * 64 + n * 16 + r16;
        float val = acc[i][n][j] + bias[col];
        if (MODE == 0) {
          outF[(size_t)row * N + col] = val;
        } else {
          int which = col >> 10, c = col & 1023;
          int h = c >> 6, d = c & 63;
          int b = row >> 11, t = row & 2047;
          if (which == 2) {
            // sigma-permute key index within its 32-block
            int k5 = t & 31;
            int p = (k5 < 16) ? ((k5 >> 2) * 8 + (k5 & 3))
                              : (((k5 - 16) >> 2) * 8 + 4 + ((k5 - 16) & 3));
            int tp = (t & ~31) | p;
            outQKV[2 * (size_t)QKV_ELEMS +
                   (((size_t)(b * 16 + h) * 64 + d) * 2048 + tp)] = bf16_of(val);
          } else {
            if (which == 0) val *= 0.125f;   // fold 1/sqrt(HS) into Q (exact pow2)
            outQKV[(size_t)which * QKV_ELEMS +
                   (((size_t)(b * 16 + h) * 2048 + t) * 64 + d)] = bf16_of(val);
          }
        }
      }
}

// ---------------- causal flash attention ----------------
// R12 verbatim (64-row q-block/wave, 4-strip reuse, sigma-permuted V, own-lane
// P fragments) + register double-buffer (FA/FB, static unroll-by-2 — the only
// change this round).
struct Frags {
  short8 kf0[2], kf1[2], vf[4];
};

static __device__ __forceinline__ void load_frags(Frags& f, int key0, int r16, int g4,
                                                  const unsigned short* __restrict__ Kp,
                                                  const unsigned short* __restrict__ Vp) {
#pragma unroll
  for (int c = 0; c < 2; ++c)
    f.kf0[c] = *reinterpret_cast<const short8*>(&Kp[(size_t)(key0 + r16) * 64 + c * 32 + g4 * 8]);
#pragma unroll
  for (int c = 0; c < 2; ++c)
    f.kf1[c] = *reinterpret_cast<const short8*>(&Kp[(size_t)(key0 + 16 + r16) * 64 + c * 32 + g4 * 8]);
#pragma unroll
  for (int dblk = 0; dblk < 4; ++dblk)
    f.vf[dblk] = *reinterpret_cast<const short8*>(
        &Vp[(size_t)(dblk * 16 + r16) * TT + key0 + g4 * 8]);  // sigma order
}

// MODE 0: full 32-key tile. MODE 1: kb0 full + kb1 diag. MODE 2: kb0 diag only.
template <int MODE>
static __device__ __forceinline__ void compute_tile(const Frags& f, int r16, int g4,
                                                    const short8 qf[2], f32x4 o[4],
                                                    float& m, float& lsum) {
  f32x4 zero = {0.f, 0.f, 0.f, 0.f};
  f32x4 s0 = zero, s1 = zero;
  __builtin_amdgcn_s_setprio(1);
  s0 = __builtin_amdgcn_mfma_f32_16x16x32_bf16(f.kf0[0], qf[0], s0, 0, 0, 0);
  s0 = __builtin_amdgcn_mfma_f32_16x16x32_bf16(f.kf0[1], qf[1], s0, 0, 0, 0);
  if (MODE != 2) {
    s1 = __builtin_amdgcn_mfma_f32_16x16x32_bf16(f.kf1[0], qf[0], s1, 0, 0, 0);
    s1 = __builtin_amdgcn_mfma_f32_16x16x32_bf16(f.kf1[1], qf[1], s1, 0, 0, 0);
  }
  __builtin_amdgcn_s_setprio(0);

  if (MODE == 2) {
#pragma unroll
    for (int r = 0; r < 4; ++r)
      if (g4 * 4 + r > r16) s0[r] = -1e30f;
  }
  if (MODE == 1) {
#pragma unroll
    for (int r = 0; r < 4; ++r)
      if (g4 * 4 + r > r16) s1[r] = -1e30f;
  }

  float om = fmaxf(fmaxf(s0[0], s0[1]), fmaxf(s0[2], s0[3]));
  if (MODE != 2)
    om = fmaxf(om, fmaxf(fmaxf(s1[0], s1[1]), fmaxf(s1[2], s1[3])));
  om = fmaxf(om, __shfl_xor(om, 16));
  om = fmaxf(om, __shfl_xor(om, 32));
  float mn = fmaxf(m, om);
  float alpha = __expf(m - mn);
  m = mn;

  float p0[4], p1[4];
#pragma unroll
  for (int r = 0; r < 4; ++r) {
    p0[r] = __expf(s0[r] - mn);
    if (MODE != 2) p1[r] = __expf(s1[r] - mn);
  }
  float rs = (p0[0] + p0[1]) + (p0[2] + p0[3]);
  if (MODE != 2) rs += (p1[0] + p1[1]) + (p1[2] + p1[3]);
  rs += __shfl_xor(rs, 16);
  rs += __shfl_xor(rs, 32);
  lsum = lsum * alpha + rs;
#pragma unroll
  for (int dblk = 0; dblk < 4; ++dblk)
#pragma unroll
    for (int r = 0; r < 4; ++r) o[dblk][r] *= alpha;

  // P B-fragment from the lane's OWN values (sigma key order, matches V layout)
  union { int w[4]; short8 s8; } pf;
  CVTPK(pf.w[0], p0[0], p0[1]);
  CVTPK(pf.w[1], p0[2], p0[3]);
  if (MODE != 2) {
    CVTPK(pf.w[2], p1[0], p1[1]);
    CVTPK(pf.w[3], p1[2], p1[3]);
  } else {
    pf.w[2] = 0; pf.w[3] = 0;
  }

  __builtin_amdgcn_s_setprio(1);
#pragma unroll
  for (int dblk = 0; dblk < 4; ++dblk)
    o[dblk] = __builtin_amdgcn_mfma_f32_16x16x32_bf16(f.vf[dblk], pf.s8, o[dblk], 0, 0, 0);
  __builtin_amdgcn_s_setprio(0);
}

__global__ __launch_bounds__(64, 2) void attn_kernel(const unsigned short* __restrict__ Qm,
                                                     const unsigned short* __restrict__ Km,
                                                     const unsigned short* __restrict__ Vt,
                                                     unsigned short* __restrict__ Y) {
  int lane = threadIdx.x;
  int r16 = lane & 15, g4 = lane >> 4;
  int bh = blockIdx.y;
  int a = (int)(gridDim.x - 1 - blockIdx.x); // heavy-first
  int Q0 = a * 64;
  const unsigned short* Qp = Qm + (size_t)bh * TT * HSS;
  const unsigned short* Kp = Km + (size_t)bh * TT * HSS;
  const unsigned short* Vp = Vt + (size_t)bh * HSS * TT;

  // Q fragments for 4 strips (rows Q0+16ss+r16)
  short8 qf[4][2];
#pragma unroll
  for (int ss = 0; ss < 4; ++ss)
#pragma unroll
    for (int c = 0; c < 2; ++c)
      qf[ss][c] = *reinterpret_cast<const short8*>(
          &Qp[(size_t)(Q0 + ss * 16 + r16) * 64 + c * 32 + g4 * 8]);

  f32x4 o[4][4];
#pragma unroll
  for (int ss = 0; ss < 4; ++ss)
#pragma unroll
    for (int dblk = 0; dblk < 4; ++dblk) o[ss][dblk] = f32x4{0.f, 0.f, 0.f, 0.f};
  float m[4] = {-1e30f, -1e30f, -1e30f, -1e30f};
  float l[4] = {0.f, 0.f, 0.f, 0.f};

  Frags FA, FB;
  int nfull = a * 2;
  if (nfull > 0) {
    load_frags(FA, 0, r16, g4, Kp, Vp);
    int t = 0;
    while (t + 1 < nfull) {
      load_frags(FB, (t + 1) << 5, r16, g4, Kp, Vp);
#pragma unroll
      for (int ss = 0; ss < 4; ++ss)
        compute_tile<0>(FA, r16, g4, qf[ss], o[ss], m[ss], l[ss]);
      if (t + 2 < nfull) load_frags(FA, (t + 2) << 5, r16, g4, Kp, Vp);
#pragma unroll
      for (int ss = 0; ss < 4; ++ss)
        compute_tile<0>(FB, r16, g4, qf[ss], o[ss], m[ss], l[ss]);
      t += 2;
    }
    if (t < nfull) {
#pragma unroll
      for (int ss = 0; ss < 4; ++ss)
        compute_tile<0>(FA, r16, g4, qf[ss], o[ss], m[ss], l[ss]);
    }
  }
  // tails: tile 2a (key0=Q0) in FA, tile 2a+1 (key0=Q0+32) in FB (issued early)
  load_frags(FA, Q0, r16, g4, Kp, Vp);
  load_frags(FB, Q0 + 32, r16, g4, Kp, Vp);
  compute_tile<2>(FA, r16, g4, qf[0], o[0], m[0], l[0]);
  compute_tile<1>(FA, r16, g4, qf[1], o[1], m[1], l[1]);
  compute_tile<0>(FA, r16, g4, qf[2], o[2], m[2], l[2]);
  compute_tile<0>(FA, r16, g4, qf[3], o[3], m[3], l[3]);
  compute_tile<2>(FB, r16, g4, qf[2], o[2], m[2], l[2]);
  compute_tile<1>(FB, r16, g4, qf[3], o[3], m[3], l[3]);

  // epilogue
  int b = bh >> 4, h = bh & 15;
#pragma unroll
  for (int ss = 0; ss < 4; ++ss) {
    float inv = 1.0f / l[ss];
    unsigned short* yrow = Y + ((size_t)(b * TT + Q0 + ss * 16 + r16) * CCH) + h * 64;
#pragma unroll
    for (int dblk = 0; dblk < 4; ++dblk) {
      float v0 = o[ss][dblk][0] * inv, v1 = o[ss][dblk][1] * inv;
      float v2 = o[ss][dblk][2] * inv, v3 = o[ss][dblk][3] * inv;
      int wa, wb;
      CVTPK(wa, v0, v1);
      CVTPK(wb, v2, v3);
      int2 pk; pk.x = wa; pk.y = wb;
      *reinterpret_cast<int2*>(&yrow[dblk * 16 + g4 * 4]) = pk;
    }
  }
}

// ---------------- host ----------------
extern "C" void kernel_launch(void* const* d_in, const int* in_sizes, int n_in,
                              void* d_out, int out_size, void* d_ws, size_t ws_size,
                              hipStream_t stream) {
  const float* x      = (const float*)d_in[0];
  const float* w_attn = (const float*)d_in[1];
  const float* b_attn = (const float*)d_in[2];
  const float* w_proj = (const float*)d_in[3];
  const float* b_proj = (const float*)d_in[4];
  float* out = (float*)d_out;

  char* ws = (char*)d_ws;
  unsigned short* xb  = (unsigned short*)(ws + 0);          // 8192x1024 bf16; reused as Y
  unsigned short* wta = (unsigned short*)(ws + 16777216);   // 3072x1024 bf16
  unsigned short* wtp = (unsigned short*)(ws + 23068672);   // 1024x1024 bf16
  unsigned short* qb  = (unsigned short*)(ws + 25165824);   // q,k: [64][2048][64]; vt(sigma): [64][64][2048]
  unsigned short* yb  = xb;

  cast_f32_bf16<<<(MROWS * CCH) / 1024, 256, 0, stream>>>(x, xb, MROWS * CCH);
  transpose_cast<<<(CCH * 3 * CCH + 255) / 256, 256, 0, stream>>>(w_attn, wta, CCH, 3 * CCH);
  transpose_cast<<<(CCH * CCH + 255) / 256, 256, 0, stream>>>(w_proj, wtp, CCH, CCH);

  {
    dim3 grid(3 * CCH / 128, MROWS / 128);   // 24 x 64 = 1536 (%8==0, swizzle bijective)
    gemm_bt<1><<<grid, 256, 0, stream>>>(xb, wta, b_attn, nullptr, qb, MROWS, 3 * CCH, CCH);
  }
  {
    dim3 grid(TT / 64, BB * NHH);   // 32 q-blocks x 64 bh, 1 wave each
    attn_kernel<<<grid, 64, 0, stream>>>(qb, qb + (size_t)QKV_ELEMS, qb + 2 * (size_t)QKV_ELEMS, yb);
  }
  {
    dim3 grid(CCH / 128, MROWS / 128);       // 8 x 64 = 512 (%8==0)
    gemm_bt<0><<<grid, 256, 0, stream>>>(yb, wtp, b_proj, out, nullptr, MROWS, CCH, CCH);
  }
}

// Round 15
// 279.657 us; speedup vs baseline: 1.2518x; 1.0123x over previous
//
#include <hip/hip_runtime.h>
#include <hip/hip_bf16.h>

// Problem constants
#define BB 4
#define TT 2048
#define CCH 1024
#define NHH 16
#define HSS 64
#define MROWS (BB * TT)            // 8192
#define QKV_ELEMS (64 * 2048 * 64) // per-tensor elems = 8388608

typedef __attribute__((ext_vector_type(8))) short short8;
typedef __attribute__((ext_vector_type(4))) float f32x4;

#define CVTPK(d, a, b) asm("v_cvt_pk_bf16_f32 %0, %1, %2" : "=v"(d) : "v"(a), "v"(b))

static __device__ __forceinline__ unsigned short bf16_of(float f) {
  union { float f; unsigned u; } v; v.f = f;
  unsigned u = v.u;
  return (unsigned short)((u + 0x7FFFu + ((u >> 16) & 1u)) >> 16);
}

// ---------------- cast kernels ----------------
__global__ __launch_bounds__(256) void cast_f32_bf16(const float* __restrict__ in,
                                                     unsigned short* __restrict__ out, int n) {
  int i = (blockIdx.x * 256 + threadIdx.x) * 4;
  if (i < n) {
    float4 f = *reinterpret_cast<const float4*>(in + i);
    ushort4 o;
    o.x = bf16_of(f.x); o.y = bf16_of(f.y); o.z = bf16_of(f.z); o.w = bf16_of(f.w);
    *reinterpret_cast<ushort4*>(out + i) = o;
  }
}

// in: [K][N] f32 row-major -> out: [N][K] bf16 row-major (LDS 32x32 tiled)
__global__ __launch_bounds__(256) void transpose_cast(const float* __restrict__ in,
                                                      unsigned short* __restrict__ out,
                                                      int K, int N) {
  __shared__ float tile[32][33];
  int k0 = blockIdx.y * 32, n0 = blockIdx.x * 32;
  int tx = threadIdx.x & 31, ty = threadIdx.x >> 5;   // ty = 0..7
#pragma unroll
  for (int i = 0; i < 4; ++i)
    tile[ty + 8 * i][tx] = in[(size_t)(k0 + ty + 8 * i) * N + n0 + tx];
  __syncthreads();
#pragma unroll
  for (int i = 0; i < 4; ++i)
    out[(size_t)(n0 + ty + 8 * i) * K + k0 + tx] = bf16_of(tile[tx][ty + 8 * i]);
}

// ---------------- GEMM: C = A[M,K] @ Bt[N,K]^T + bias (verified R1-R3, R12 epilogue) ----
template <int MODE>
__global__ __launch_bounds__(256) void gemm_bt(const unsigned short* __restrict__ A,
                                               const unsigned short* __restrict__ Bt,
                                               const float* __restrict__ bias,
                                               float* __restrict__ outF,
                                               unsigned short* __restrict__ outQKV,
                                               int M, int N, int K) {
  __shared__ unsigned short As[128 * 32];
  __shared__ unsigned short Bs[128 * 32];
  int tid = threadIdx.x;
  int w = tid >> 6, lane = tid & 63;
  int g = lane >> 4, r16 = lane & 15;
  int wr = w >> 1, wc = w & 1;

  // XCD swizzle: contiguous per-XCD tile range (nwg % 8 == 0)
  int nwg = (int)(gridDim.x * gridDim.y);
  int id = (int)(blockIdx.y * gridDim.x + blockIdx.x);
  int cpx = nwg >> 3;
  int swz = (id & 7) * cpx + (id >> 3);
  int m0 = (swz / (int)gridDim.x) * 128;
  int n0 = (swz % (int)gridDim.x) * 128;

  int lrow = lane >> 2;
  int lcol = (lane & 3) * 8;

  f32x4 zero = {0.f, 0.f, 0.f, 0.f};
  f32x4 acc[4][4];
#pragma unroll
  for (int i = 0; i < 4; ++i)
#pragma unroll
    for (int n = 0; n < 4; ++n) acc[i][n] = zero;

  for (int kt = 0; kt < K; kt += 32) {
#pragma unroll
    for (int c = 0; c < 2; ++c) {
      int rg = w * 32 + c * 16;
      __builtin_amdgcn_global_load_lds(
          (const __attribute__((address_space(1))) void*)(&A[(size_t)(m0 + rg + lrow) * K + kt + lcol]),
          (__attribute__((address_space(3))) void*)(&As[rg * 32]), 16, 0, 0);
      __builtin_amdgcn_global_load_lds(
          (const __attribute__((address_space(1))) void*)(&Bt[(size_t)(n0 + rg + lrow) * K + kt + lcol]),
          (__attribute__((address_space(3))) void*)(&Bs[rg * 32]), 16, 0, 0);
    }
    __syncthreads();
    short8 af[4], bfr[4];
#pragma unroll
    for (int i = 0; i < 4; ++i)
      af[i] = *reinterpret_cast<const short8*>(&As[(wr * 64 + i * 16 + r16) * 32 + g * 8]);
#pragma unroll
    for (int i = 0; i < 4; ++i)
      bfr[i] = *reinterpret_cast<const short8*>(&Bs[(wc * 64 + i * 16 + r16) * 32 + g * 8]);
#pragma unroll
    for (int i = 0; i < 4; ++i)
#pragma unroll
      for (int n = 0; n < 4; ++n)
        acc[i][n] = __builtin_amdgcn_mfma_f32_16x16x32_bf16(af[i], bfr[n], acc[i][n], 0, 0, 0);
    __syncthreads();
  }

#pragma unroll
  for (int i = 0; i < 4; ++i)
#pragma unroll
    for (int n = 0; n < 4; ++n)
#pragma unroll
      for (int j = 0; j < 4; ++j) {
        int row = m0 + wr * 64 + i * 16 + g * 4 + j;
        int col = n0 + wc * 64 + n * 16 + r16;
        float val = acc[i][n][j] + bias[col];
        if (MODE == 0) {
          outF[(size_t)row * N + col] = val;
        } else {
          int which = col >> 10, c = col & 1023;
          int h = c >> 6, d = c & 63;
          int b = row >> 11, t = row & 2047;
          if (which == 2) {
            // sigma-permute key index within its 32-block
            int k5 = t & 31;
            int p = (k5 < 16) ? ((k5 >> 2) * 8 + (k5 & 3))
                              : (((k5 - 16) >> 2) * 8 + 4 + ((k5 - 16) & 3));
            int tp = (t & ~31) | p;
            outQKV[2 * (size_t)QKV_ELEMS +
                   (((size_t)(b * 16 + h) * 64 + d) * 2048 + tp)] = bf16_of(val);
          } else {
            if (which == 0) val *= 0.125f;   // fold 1/sqrt(HS) into Q (exact pow2)
            outQKV[(size_t)which * QKV_ELEMS +
                   (((size_t)(b * 16 + h) * 2048 + t) * 64 + d)] = bf16_of(val);
          }
        }
      }
}

// ---------------- causal flash attention: split-K x2 (guarded merge) ----------------
// R12 compute verbatim. Block = 2 waves; uniform main loop t = wv*a + i.
// wave0: + tail tile 2a (modes 2,1,0,0). wave1: + tail tile 2a+1 (modes -,-,2,1),
// publishes partials to LDS. Merge gates every wave1 term behind has1 = (l1>0).
struct Frags {
  short8 kf0[2], kf1[2], vf[4];
};

static __device__ __forceinline__ void load_frags(Frags& f, int key0, int r16, int g4,
                                                  const unsigned short* __restrict__ Kp,
                                                  const unsigned short* __restrict__ Vp) {
#pragma unroll
  for (int c = 0; c < 2; ++c)
    f.kf0[c] = *reinterpret_cast<const short8*>(&Kp[(size_t)(key0 + r16) * 64 + c * 32 + g4 * 8]);
#pragma unroll
  for (int c = 0; c < 2; ++c)
    f.kf1[c] = *reinterpret_cast<const short8*>(&Kp[(size_t)(key0 + 16 + r16) * 64 + c * 32 + g4 * 8]);
#pragma unroll
  for (int dblk = 0; dblk < 4; ++dblk)
    f.vf[dblk] = *reinterpret_cast<const short8*>(
        &Vp[(size_t)(dblk * 16 + r16) * TT + key0 + g4 * 8]);  // sigma order
}

// MODE 0: full 32-key tile. MODE 1: kb0 full + kb1 diag. MODE 2: kb0 diag only.
template <int MODE>
static __device__ __forceinline__ void compute_tile(const Frags& f, int r16, int g4,
                                                    const short8 qf[2], f32x4 o[4],
                                                    float& m, float& lsum) {
  f32x4 zero = {0.f, 0.f, 0.f, 0.f};
  f32x4 s0 = zero, s1 = zero;
  __builtin_amdgcn_s_setprio(1);
  s0 = __builtin_amdgcn_mfma_f32_16x16x32_bf16(f.kf0[0], qf[0], s0, 0, 0, 0);
  s0 = __builtin_amdgcn_mfma_f32_16x16x32_bf16(f.kf0[1], qf[1], s0, 0, 0, 0);
  if (MODE != 2) {
    s1 = __builtin_amdgcn_mfma_f32_16x16x32_bf16(f.kf1[0], qf[0], s1, 0, 0, 0);
    s1 = __builtin_amdgcn_mfma_f32_16x16x32_bf16(f.kf1[1], qf[1], s1, 0, 0, 0);
  }
  __builtin_amdgcn_s_setprio(0);

  if (MODE == 2) {
#pragma unroll
    for (int r = 0; r < 4; ++r)
      if (g4 * 4 + r > r16) s0[r] = -1e30f;
  }
  if (MODE == 1) {
#pragma unroll
    for (int r = 0; r < 4; ++r)
      if (g4 * 4 + r > r16) s1[r] = -1e30f;
  }

  float om = fmaxf(fmaxf(s0[0], s0[1]), fmaxf(s0[2], s0[3]));
  if (MODE != 2)
    om = fmaxf(om, fmaxf(fmaxf(s1[0], s1[1]), fmaxf(s1[2], s1[3])));
  om = fmaxf(om, __shfl_xor(om, 16));
  om = fmaxf(om, __shfl_xor(om, 32));
  float mn = fmaxf(m, om);
  float alpha = __expf(m - mn);
  m = mn;

  float p0[4], p1[4];
#pragma unroll
  for (int r = 0; r < 4; ++r) {
    p0[r] = __expf(s0[r] - mn);
    if (MODE != 2) p1[r] = __expf(s1[r] - mn);
  }
  float rs = (p0[0] + p0[1]) + (p0[2] + p0[3]);
  if (MODE != 2) rs += (p1[0] + p1[1]) + (p1[2] + p1[3]);
  rs += __shfl_xor(rs, 16);
  rs += __shfl_xor(rs, 32);
  lsum = lsum * alpha + rs;
#pragma unroll
  for (int dblk = 0; dblk < 4; ++dblk)
#pragma unroll
    for (int r = 0; r < 4; ++r) o[dblk][r] *= alpha;

  union { int w[4]; short8 s8; } pf;
  CVTPK(pf.w[0], p0[0], p0[1]);
  CVTPK(pf.w[1], p0[2], p0[3]);
  if (MODE != 2) {
    CVTPK(pf.w[2], p1[0], p1[1]);
    CVTPK(pf.w[3], p1[2], p1[3]);
  } else {
    pf.w[2] = 0; pf.w[3] = 0;
  }

  __builtin_amdgcn_s_setprio(1);
#pragma unroll
  for (int dblk = 0; dblk < 4; ++dblk)
    o[dblk] = __builtin_amdgcn_mfma_f32_16x16x32_bf16(f.vf[dblk], pf.s8, o[dblk], 0, 0, 0);
  __builtin_amdgcn_s_setprio(0);
}

__global__ __launch_bounds__(128, 2) void attn_kernel(const unsigned short* __restrict__ Qm,
                                                      const unsigned short* __restrict__ Km,
                                                      const unsigned short* __restrict__ Vt,
                                                      unsigned short* __restrict__ Y) {
  __shared__ float smem[64][72];   // wave1 partials: o(64) + m(4) + l(4) per lane

  int tid = threadIdx.x;
  int wv = tid >> 6, lane = tid & 63;
  int r16 = lane & 15, g4 = lane >> 4;
  int bh = blockIdx.y;
  int a = (int)(gridDim.x - 1 - blockIdx.x); // heavy-first
  int Q0 = a * 64;
  const unsigned short* Qp = Qm + (size_t)bh * TT * HSS;
  const unsigned short* Kp = Km + (size_t)bh * TT * HSS;
  const unsigned short* Vp = Vt + (size_t)bh * HSS * TT;

  short8 qf[4][2];
#pragma unroll
  for (int ss = 0; ss < 4; ++ss)
#pragma unroll
    for (int c = 0; c < 2; ++c)
      qf[ss][c] = *reinterpret_cast<const short8*>(
          &Qp[(size_t)(Q0 + ss * 16 + r16) * 64 + c * 32 + g4 * 8]);

  f32x4 o[4][4];
#pragma unroll
  for (int ss = 0; ss < 4; ++ss)
#pragma unroll
    for (int dblk = 0; dblk < 4; ++dblk) o[ss][dblk] = f32x4{0.f, 0.f, 0.f, 0.f};
  float m[4] = {-1e30f, -1e30f, -1e30f, -1e30f};
  float l[4] = {0.f, 0.f, 0.f, 0.f};

  Frags F;
  // uniform main loop: both waves run exactly a iterations
  int tbase = wv * a;
  for (int i = 0; i < a; ++i) {
    load_frags(F, (tbase + i) << 5, r16, g4, Kp, Vp);
#pragma unroll
    for (int ss = 0; ss < 4; ++ss)
      compute_tile<0>(F, r16, g4, qf[ss], o[ss], m[ss], l[ss]);
  }
  // tail: wave wv handles tile 2a+wv
  load_frags(F, Q0 + wv * 32, r16, g4, Kp, Vp);
  if (wv == 0) {
    compute_tile<2>(F, r16, g4, qf[0], o[0], m[0], l[0]);
    compute_tile<1>(F, r16, g4, qf[1], o[1], m[1], l[1]);
    compute_tile<0>(F, r16, g4, qf[2], o[2], m[2], l[2]);
    compute_tile<0>(F, r16, g4, qf[3], o[3], m[3], l[3]);
  } else {
    compute_tile<2>(F, r16, g4, qf[2], o[2], m[2], l[2]);
    compute_tile<1>(F, r16, g4, qf[3], o[3], m[3], l[3]);
    // publish partials
#pragma unroll
    for (int ss = 0; ss < 4; ++ss) {
#pragma unroll
      for (int dblk = 0; dblk < 4; ++dblk)
#pragma unroll
        for (int r = 0; r < 4; ++r)
          smem[lane][ss * 16 + dblk * 4 + r] = o[ss][dblk][r];
      smem[lane][64 + ss] = m[ss];
      smem[lane][68 + ss] = l[ss];
    }
  }
  __syncthreads();

  if (wv == 0) {
    int b = bh >> 4, h = bh & 15;
#pragma unroll
    for (int ss = 0; ss < 4; ++ss) {
      float m1 = smem[lane][64 + ss];
      float l1 = smem[lane][68 + ss];
      bool has1 = (l1 > 0.0f);             // false for empty strips, garbage, NaN
      float M = has1 ? fmaxf(m[ss], m1) : m[ss];
      float a0 = __expf(m[ss] - M);
      float a1 = has1 ? __expf(m1 - M) : 0.0f;
      float L = l[ss] * a0 + (has1 ? l1 * a1 : 0.0f);
      float inv = 1.0f / L;
      unsigned short* yrow = Y + ((size_t)(b * TT + Q0 + ss * 16 + r16) * CCH) + h * 64;
#pragma unroll
      for (int dblk = 0; dblk < 4; ++dblk) {
        float v[4];
#pragma unroll
        for (int r = 0; r < 4; ++r) {
          float o1v = has1 ? smem[lane][ss * 16 + dblk * 4 + r] * a1 : 0.0f;
          v[r] = (o[ss][dblk][r] * a0 + o1v) * inv;
        }
        int wa, wb;
        CVTPK(wa, v[0], v[1]);
        CVTPK(wb, v[2], v[3]);
        int2 pk; pk.x = wa; pk.y = wb;
        *reinterpret_cast<int2*>(&yrow[dblk * 16 + g4 * 4]) = pk;
      }
    }
  }
}

// ---------------- host ----------------
extern "C" void kernel_launch(void* const* d_in, const int* in_sizes, int n_in,
                              void* d_out, int out_size, void* d_ws, size_t ws_size,
                              hipStream_t stream) {
  const float* x      = (const float*)d_in[0];
  const float* w_attn = (const float*)d_in[1];
  const float* b_attn = (const float*)d_in[2];
  const float* w_proj = (const float*)d_in[3];
  const float* b_proj = (const float*)d_in[4];
  float* out = (float*)d_out;

  char* ws = (char*)d_ws;
  unsigned short* xb  = (unsigned short*)(ws + 0);          // 8192x1024 bf16; reused as Y
  unsigned short* wta = (unsigned short*)(ws + 16777216);   // 3072x1024 bf16
  unsigned short* wtp = (unsigned short*)(ws + 23068672);   // 1024x1024 bf16
  unsigned short* qb  = (unsigned short*)(ws + 25165824);   // q,k: [64][2048][64]; vt(sigma): [64][64][2048]
  unsigned short* yb  = xb;

  cast_f32_bf16<<<(MROWS * CCH) / 1024, 256, 0, stream>>>(x, xb, MROWS * CCH);
  transpose_cast<<<dim3(3 * CCH / 32, CCH / 32), 256, 0, stream>>>(w_attn, wta, CCH, 3 * CCH);
  transpose_cast<<<dim3(CCH / 32, CCH / 32), 256, 0, stream>>>(w_proj, wtp, CCH, CCH);

  {
    dim3 grid(3 * CCH / 128, MROWS / 128);   // 24 x 64 = 1536 (%8==0)
    gemm_bt<1><<<grid, 256, 0, stream>>>(xb, wta, b_attn, nullptr, qb, MROWS, 3 * CCH, CCH);
  }
  {
    dim3 grid(TT / 64, BB * NHH);   // 32 q-blocks x 64 bh, 2 waves each (split-K)
    attn_kernel<<<grid, 128, 0, stream>>>(qb, qb + (size_t)QKV_ELEMS, qb + 2 * (size_t)QKV_ELEMS, yb);
  }
  {
    dim3 grid(CCH / 128, MROWS / 128);       // 8 x 64 = 512 (%8==0)
    gemm_bt<0><<<grid, 256, 0, stream>>>(yb, wtp, b_proj, out, nullptr, MROWS, CCH, CCH);
  }
}

// Round 16
// 267.202 us; speedup vs baseline: 1.3101x; 1.0466x over previous
//
#include <hip/hip_runtime.h>
#include <hip/hip_bf16.h>

// Problem constants
#define BB 4
#define TT 2048
#define CCH 1024
#define NHH 16
#define HSS 64
#define MROWS (BB * TT)            // 8192
#define QKV_ELEMS (64 * 2048 * 64) // per-tensor elems = 8388608

typedef __attribute__((ext_vector_type(8))) short short8;
typedef __attribute__((ext_vector_type(4))) float f32x4;

#define CVTPK(d, a, b) asm("v_cvt_pk_bf16_f32 %0, %1, %2" : "=v"(d) : "v"(a), "v"(b))

static __device__ __forceinline__ unsigned short bf16_of(float f) {
  union { float f; unsigned u; } v; v.f = f;
  unsigned u = v.u;
  return (unsigned short)((u + 0x7FFFu + ((u >> 16) & 1u)) >> 16);
}

// ---------------- cast kernels ----------------
__global__ __launch_bounds__(256) void cast_f32_bf16(const float* __restrict__ in,
                                                     unsigned short* __restrict__ out, int n) {
  int i = (blockIdx.x * 256 + threadIdx.x) * 4;
  if (i < n) {
    float4 f = *reinterpret_cast<const float4*>(in + i);
    ushort4 o;
    o.x = bf16_of(f.x); o.y = bf16_of(f.y); o.z = bf16_of(f.z); o.w = bf16_of(f.w);
    *reinterpret_cast<ushort4*>(out + i) = o;
  }
}

// in: [K][N] f32 row-major -> out: [N][K] bf16 row-major (LDS 32x32 tiled)
__global__ __launch_bounds__(256) void transpose_cast(const float* __restrict__ in,
                                                      unsigned short* __restrict__ out,
                                                      int K, int N) {
  __shared__ float tile[32][33];
  int k0 = blockIdx.y * 32, n0 = blockIdx.x * 32;
  int tx = threadIdx.x & 31, ty = threadIdx.x >> 5;   // ty = 0..7
#pragma unroll
  for (int i = 0; i < 4; ++i)
    tile[ty + 8 * i][tx] = in[(size_t)(k0 + ty + 8 * i) * N + n0 + tx];
  __syncthreads();
#pragma unroll
  for (int i = 0; i < 4; ++i)
    out[(size_t)(n0 + ty + 8 * i) * K + k0 + tx] = bf16_of(tile[tx][ty + 8 * i]);
}

// ---------------- GEMM: C = A[M,K] @ Bt[N,K]^T + bias (verified R1-R3, R12 epilogue) ----
template <int MODE>
__global__ __launch_bounds__(256) void gemm_bt(const unsigned short* __restrict__ A,
                                               const unsigned short* __restrict__ Bt,
                                               const float* __restrict__ bias,
                                               float* __restrict__ outF,
                                               unsigned short* __restrict__ outQKV,
                                               int M, int N, int K) {
  __shared__ unsigned short As[128 * 32];
  __shared__ unsigned short Bs[128 * 32];
  int tid = threadIdx.x;
  int w = tid >> 6, lane = tid & 63;
  int g = lane >> 4, r16 = lane & 15;
  int wr = w >> 1, wc = w & 1;

  // XCD swizzle: contiguous per-XCD tile range (nwg % 8 == 0)
  int nwg = (int)(gridDim.x * gridDim.y);
  int id = (int)(blockIdx.y * gridDim.x + blockIdx.x);
  int cpx = nwg >> 3;
  int swz = (id & 7) * cpx + (id >> 3);
  int m0 = (swz / (int)gridDim.x) * 128;
  int n0 = (swz % (int)gridDim.x) * 128;

  int lrow = lane >> 2;
  int lcol = (lane & 3) * 8;

  f32x4 zero = {0.f, 0.f, 0.f, 0.f};
  f32x4 acc[4][4];
#pragma unroll
  for (int i = 0; i < 4; ++i)
#pragma unroll
    for (int n = 0; n < 4; ++n) acc[i][n] = zero;

  for (int kt = 0; kt < K; kt += 32) {
#pragma unroll
    for (int c = 0; c < 2; ++c) {
      int rg = w * 32 + c * 16;
      __builtin_amdgcn_global_load_lds(
          (const __attribute__((address_space(1))) void*)(&A[(size_t)(m0 + rg + lrow) * K + kt + lcol]),
          (__attribute__((address_space(3))) void*)(&As[rg * 32]), 16, 0, 0);
      __builtin_amdgcn_global_load_lds(
          (const __attribute__((address_space(1))) void*)(&Bt[(size_t)(n0 + rg + lrow) * K + kt + lcol]),
          (__attribute__((address_space(3))) void*)(&Bs[rg * 32]), 16, 0, 0);
    }
    __syncthreads();
    short8 af[4], bfr[4];
#pragma unroll
    for (int i = 0; i < 4; ++i)
      af[i] = *reinterpret_cast<const short8*>(&As[(wr * 64 + i * 16 + r16) * 32 + g * 8]);
#pragma unroll
    for (int i = 0; i < 4; ++i)
      bfr[i] = *reinterpret_cast<const short8*>(&Bs[(wc * 64 + i * 16 + r16) * 32 + g * 8]);
#pragma unroll
    for (int i = 0; i < 4; ++i)
#pragma unroll
      for (int n = 0; n < 4; ++n)
        acc[i][n] = __builtin_amdgcn_mfma_f32_16x16x32_bf16(af[i], bfr[n], acc[i][n], 0, 0, 0);
    __syncthreads();
  }

#pragma unroll
  for (int i = 0; i < 4; ++i)
#pragma unroll
    for (int n = 0; n < 4; ++n)
#pragma unroll
      for (int j = 0; j < 4; ++j) {
        int row = m0 + wr * 64 + i * 16 + g * 4 + j;
        int col = n0 + wc * 64 + n * 16 + r16;
        float val = acc[i][n][j] + bias[col];
        if (MODE == 0) {
          outF[(size_t)row * N + col] = val;
        } else {
          int which = col >> 10, c = col & 1023;
          int h = c >> 6, d = c & 63;
          int b = row >> 11, t = row & 2047;
          if (which == 2) {
            // sigma-permute key index within its 32-block
            int k5 = t & 31;
            int p = (k5 < 16) ? ((k5 >> 2) * 8 + (k5 & 3))
                              : (((k5 - 16) >> 2) * 8 + 4 + ((k5 - 16) & 3));
            int tp = (t & ~31) | p;
            outQKV[2 * (size_t)QKV_ELEMS +
                   (((size_t)(b * 16 + h) * 64 + d) * 2048 + tp)] = bf16_of(val);
          } else {
            if (which == 0) val *= 0.125f;   // fold 1/sqrt(HS) into Q (exact pow2)
            outQKV[(size_t)which * QKV_ELEMS +
                   (((size_t)(b * 16 + h) * 2048 + t) * 64 + d)] = bf16_of(val);
          }
        }
      }
}

// ---------------- causal flash attention (R12 snapshot, best measured: 137 us) --------
// 64-row q-block per wave, 4-strip reuse per tile-load, sigma-permuted V so the
// PV B-fragment is the lane's own p-values (zero crossbar ops in the P path).
struct Frags {
  short8 kf0[2], kf1[2], vf[4];
};

static __device__ __forceinline__ void load_frags(Frags& f, int key0, int r16, int g4,
                                                  const unsigned short* __restrict__ Kp,
                                                  const unsigned short* __restrict__ Vp) {
#pragma unroll
  for (int c = 0; c < 2; ++c)
    f.kf0[c] = *reinterpret_cast<const short8*>(&Kp[(size_t)(key0 + r16) * 64 + c * 32 + g4 * 8]);
#pragma unroll
  for (int c = 0; c < 2; ++c)
    f.kf1[c] = *reinterpret_cast<const short8*>(&Kp[(size_t)(key0 + 16 + r16) * 64 + c * 32 + g4 * 8]);
#pragma unroll
  for (int dblk = 0; dblk < 4; ++dblk)
    f.vf[dblk] = *reinterpret_cast<const short8*>(
        &Vp[(size_t)(dblk * 16 + r16) * TT + key0 + g4 * 8]);  // sigma order
}

// MODE 0: full 32-key tile. MODE 1: kb0 full + kb1 diag. MODE 2: kb0 diag only.
template <int MODE>
static __device__ __forceinline__ void compute_tile(const Frags& f, int r16, int g4,
                                                    const short8 qf[2], f32x4 o[4],
                                                    float& m, float& lsum) {
  f32x4 zero = {0.f, 0.f, 0.f, 0.f};
  f32x4 s0 = zero, s1 = zero;
  __builtin_amdgcn_s_setprio(1);
  s0 = __builtin_amdgcn_mfma_f32_16x16x32_bf16(f.kf0[0], qf[0], s0, 0, 0, 0);
  s0 = __builtin_amdgcn_mfma_f32_16x16x32_bf16(f.kf0[1], qf[1], s0, 0, 0, 0);
  if (MODE != 2) {
    s1 = __builtin_amdgcn_mfma_f32_16x16x32_bf16(f.kf1[0], qf[0], s1, 0, 0, 0);
    s1 = __builtin_amdgcn_mfma_f32_16x16x32_bf16(f.kf1[1], qf[1], s1, 0, 0, 0);
  }
  __builtin_amdgcn_s_setprio(0);

  if (MODE == 2) {
#pragma unroll
    for (int r = 0; r < 4; ++r)
      if (g4 * 4 + r > r16) s0[r] = -1e30f;
  }
  if (MODE == 1) {
#pragma unroll
    for (int r = 0; r < 4; ++r)
      if (g4 * 4 + r > r16) s1[r] = -1e30f;
  }

  float om = fmaxf(fmaxf(s0[0], s0[1]), fmaxf(s0[2], s0[3]));
  if (MODE != 2)
    om = fmaxf(om, fmaxf(fmaxf(s1[0], s1[1]), fmaxf(s1[2], s1[3])));
  om = fmaxf(om, __shfl_xor(om, 16));
  om = fmaxf(om, __shfl_xor(om, 32));
  float mn = fmaxf(m, om);
  float alpha = __expf(m - mn);
  m = mn;

  float p0[4], p1[4];
#pragma unroll
  for (int r = 0; r < 4; ++r) {
    p0[r] = __expf(s0[r] - mn);
    if (MODE != 2) p1[r] = __expf(s1[r] - mn);
  }
  float rs = (p0[0] + p0[1]) + (p0[2] + p0[3]);
  if (MODE != 2) rs += (p1[0] + p1[1]) + (p1[2] + p1[3]);
  rs += __shfl_xor(rs, 16);
  rs += __shfl_xor(rs, 32);
  lsum = lsum * alpha + rs;
#pragma unroll
  for (int dblk = 0; dblk < 4; ++dblk)
#pragma unroll
    for (int r = 0; r < 4; ++r) o[dblk][r] *= alpha;

  // P B-fragment from the lane's OWN values (sigma key order, matches V layout)
  union { int w[4]; short8 s8; } pf;
  CVTPK(pf.w[0], p0[0], p0[1]);
  CVTPK(pf.w[1], p0[2], p0[3]);
  if (MODE != 2) {
    CVTPK(pf.w[2], p1[0], p1[1]);
    CVTPK(pf.w[3], p1[2], p1[3]);
  } else {
    pf.w[2] = 0; pf.w[3] = 0;
  }

  __builtin_amdgcn_s_setprio(1);
#pragma unroll
  for (int dblk = 0; dblk < 4; ++dblk)
    o[dblk] = __builtin_amdgcn_mfma_f32_16x16x32_bf16(f.vf[dblk], pf.s8, o[dblk], 0, 0, 0);
  __builtin_amdgcn_s_setprio(0);
}

__global__ __launch_bounds__(64, 2) void attn_kernel(const unsigned short* __restrict__ Qm,
                                                     const unsigned short* __restrict__ Km,
                                                     const unsigned short* __restrict__ Vt,
                                                     unsigned short* __restrict__ Y) {
  int lane = threadIdx.x;
  int r16 = lane & 15, g4 = lane >> 4;
  int bh = blockIdx.y;
  int a = (int)(gridDim.x - 1 - blockIdx.x); // heavy-first
  int Q0 = a * 64;
  const unsigned short* Qp = Qm + (size_t)bh * TT * HSS;
  const unsigned short* Kp = Km + (size_t)bh * TT * HSS;
  const unsigned short* Vp = Vt + (size_t)bh * HSS * TT;

  // Q fragments for 4 strips (rows Q0+16ss+r16)
  short8 qf[4][2];
#pragma unroll
  for (int ss = 0; ss < 4; ++ss)
#pragma unroll
    for (int c = 0; c < 2; ++c)
      qf[ss][c] = *reinterpret_cast<const short8*>(
          &Qp[(size_t)(Q0 + ss * 16 + r16) * 64 + c * 32 + g4 * 8]);

  f32x4 o[4][4];
#pragma unroll
  for (int ss = 0; ss < 4; ++ss)
#pragma unroll
    for (int dblk = 0; dblk < 4; ++dblk) o[ss][dblk] = f32x4{0.f, 0.f, 0.f, 0.f};
  float m[4] = {-1e30f, -1e30f, -1e30f, -1e30f};
  float l[4] = {0.f, 0.f, 0.f, 0.f};

  Frags F;
  // tiles full for all 4 strips: t = 0 .. 2a-1
  int nfull = a * 2;
  for (int t = 0; t < nfull; ++t) {
    load_frags(F, t << 5, r16, g4, Kp, Vp);
#pragma unroll
    for (int ss = 0; ss < 4; ++ss)
      compute_tile<0>(F, r16, g4, qf[ss], o[ss], m[ss], l[ss]);
  }
  // tile 2a (key0 = Q0): ss0 diag(M2), ss1 M1, ss2/ss3 full
  load_frags(F, Q0, r16, g4, Kp, Vp);
  compute_tile<2>(F, r16, g4, qf[0], o[0], m[0], l[0]);
  compute_tile<1>(F, r16, g4, qf[1], o[1], m[1], l[1]);
  compute_tile<0>(F, r16, g4, qf[2], o[2], m[2], l[2]);
  compute_tile<0>(F, r16, g4, qf[3], o[3], m[3], l[3]);
  // tile 2a+1 (key0 = Q0+32): ss2 M2, ss3 M1
  load_frags(F, Q0 + 32, r16, g4, Kp, Vp);
  compute_tile<2>(F, r16, g4, qf[2], o[2], m[2], l[2]);
  compute_tile<1>(F, r16, g4, qf[3], o[3], m[3], l[3]);

  // epilogue
  int b = bh >> 4, h = bh & 15;
#pragma unroll
  for (int ss = 0; ss < 4; ++ss) {
    float inv = 1.0f / l[ss];
    unsigned short* yrow = Y + ((size_t)(b * TT + Q0 + ss * 16 + r16) * CCH) + h * 64;
#pragma unroll
    for (int dblk = 0; dblk < 4; ++dblk) {
      float v0 = o[ss][dblk][0] * inv, v1 = o[ss][dblk][1] * inv;
      float v2 = o[ss][dblk][2] * inv, v3 = o[ss][dblk][3] * inv;
      int wa, wb;
      CVTPK(wa, v0, v1);
      CVTPK(wb, v2, v3);
      int2 pk; pk.x = wa; pk.y = wb;
      *reinterpret_cast<int2*>(&yrow[dblk * 16 + g4 * 4]) = pk;
    }
  }
}

// ---------------- host ----------------
extern "C" void kernel_launch(void* const* d_in, const int* in_sizes, int n_in,
                              void* d_out, int out_size, void* d_ws, size_t ws_size,
                              hipStream_t stream) {
  const float* x      = (const float*)d_in[0];
  const float* w_attn = (const float*)d_in[1];
  const float* b_attn = (const float*)d_in[2];
  const float* w_proj = (const float*)d_in[3];
  const float* b_proj = (const float*)d_in[4];
  float* out = (float*)d_out;

  char* ws = (char*)d_ws;
  unsigned short* xb  = (unsigned short*)(ws + 0);          // 8192x1024 bf16; reused as Y
  unsigned short* wta = (unsigned short*)(ws + 16777216);   // 3072x1024 bf16
  unsigned short* wtp = (unsigned short*)(ws + 23068672);   // 1024x1024 bf16
  unsigned short* qb  = (unsigned short*)(ws + 25165824);   // q,k: [64][2048][64]; vt(sigma): [64][64][2048]
  unsigned short* yb  = xb;

  cast_f32_bf16<<<(MROWS * CCH) / 1024, 256, 0, stream>>>(x, xb, MROWS * CCH);
  transpose_cast<<<dim3(3 * CCH / 32, CCH / 32), 256, 0, stream>>>(w_attn, wta, CCH, 3 * CCH);
  transpose_cast<<<dim3(CCH / 32, CCH / 32), 256, 0, stream>>>(w_proj, wtp, CCH, CCH);

  {
    dim3 grid(3 * CCH / 128, MROWS / 128);   // 24 x 64 = 1536 (%8==0)
    gemm_bt<1><<<grid, 256, 0, stream>>>(xb, wta, b_attn, nullptr, qb, MROWS, 3 * CCH, CCH);
  }
  {
    dim3 grid(TT / 64, BB * NHH);   // 32 q-blocks x 64 bh, 1 wave each
    attn_kernel<<<grid, 64, 0, stream>>>(qb, qb + (size_t)QKV_ELEMS, qb + 2 * (size_t)QKV_ELEMS, yb);
  }
  {
    dim3 grid(CCH / 128, MROWS / 128);       // 8 x 64 = 512 (%8==0)
    gemm_bt<0><<<grid, 256, 0, stream>>>(yb, wtp, b_proj, out, nullptr, MROWS, CCH, CCH);
  }
}

// Round 17
// 229.951 us; speedup vs baseline: 1.5224x; 1.1620x over previous
//
#include <hip/hip_runtime.h>
#include <hip/hip_bf16.h>

// Problem constants
#define BB 4
#define TT 2048
#define CCH 1024
#define NHH 16
#define HSS 64
#define MROWS (BB * TT)            // 8192
#define QKV_ELEMS (64 * 2048 * 64) // per-tensor elems = 8388608

typedef __attribute__((ext_vector_type(8))) short short8;
typedef __attribute__((ext_vector_type(4))) float f32x4;

#define CVTPK(d, a, b) asm("v_cvt_pk_bf16_f32 %0, %1, %2" : "=v"(d) : "v"(a), "v"(b))

static __device__ __forceinline__ unsigned short bf16_of(float f) {
  union { float f; unsigned u; } v; v.f = f;
  unsigned u = v.u;
  return (unsigned short)((u + 0x7FFFu + ((u >> 16) & 1u)) >> 16);
}

// ---------------- cast kernels ----------------
__global__ __launch_bounds__(256) void cast_f32_bf16(const float* __restrict__ in,
                                                     unsigned short* __restrict__ out, int n) {
  int i = (blockIdx.x * 256 + threadIdx.x) * 4;
  if (i < n) {
    float4 f = *reinterpret_cast<const float4*>(in + i);
    ushort4 o;
    o.x = bf16_of(f.x); o.y = bf16_of(f.y); o.z = bf16_of(f.z); o.w = bf16_of(f.w);
    *reinterpret_cast<ushort4*>(out + i) = o;
  }
}

// in: [K][N] f32 row-major -> out: [N][K] bf16 row-major (LDS 32x32 tiled)
__global__ __launch_bounds__(256) void transpose_cast(const float* __restrict__ in,
                                                      unsigned short* __restrict__ out,
                                                      int K, int N) {
  __shared__ float tile[32][33];
  int k0 = blockIdx.y * 32, n0 = blockIdx.x * 32;
  int tx = threadIdx.x & 31, ty = threadIdx.x >> 5;   // ty = 0..7
#pragma unroll
  for (int i = 0; i < 4; ++i)
    tile[ty + 8 * i][tx] = in[(size_t)(k0 + ty + 8 * i) * N + n0 + tx];
  __syncthreads();
#pragma unroll
  for (int i = 0; i < 4; ++i)
    out[(size_t)(n0 + ty + 8 * i) * K + k0 + tx] = bf16_of(tile[tx][ty + 8 * i]);
}

// ---------------- GEMM: C = A[M,K] @ Bt[N,K]^T + bias ----------------
// Single-barrier LDS double-buffer (T3 minimum recipe): STAGE next K-tile into
// buf^1, compute current buf, ONE __syncthreads per K-step (drains vmcnt+lgkm).
template <int MODE>
__global__ __launch_bounds__(256) void gemm_bt(const unsigned short* __restrict__ A,
                                               const unsigned short* __restrict__ Bt,
                                               const float* __restrict__ bias,
                                               float* __restrict__ outF,
                                               unsigned short* __restrict__ outQKV,
                                               int M, int N, int K) {
  __shared__ unsigned short As[2][128 * 32];
  __shared__ unsigned short Bs[2][128 * 32];
  int tid = threadIdx.x;
  int w = tid >> 6, lane = tid & 63;
  int g = lane >> 4, r16 = lane & 15;
  int wr = w >> 1, wc = w & 1;

  // XCD swizzle: contiguous per-XCD tile range (nwg % 8 == 0)
  int nwg = (int)(gridDim.x * gridDim.y);
  int id = (int)(blockIdx.y * gridDim.x + blockIdx.x);
  int cpx = nwg >> 3;
  int swz = (id & 7) * cpx + (id >> 3);
  int m0 = (swz / (int)gridDim.x) * 128;
  int n0 = (swz % (int)gridDim.x) * 128;

  int lrow = lane >> 2;
  int lcol = (lane & 3) * 8;

#define STAGE_GEMM(buf, kt)                                                                  \
  {                                                                                          \
    _Pragma("unroll")                                                                        \
    for (int c = 0; c < 2; ++c) {                                                            \
      int rg = w * 32 + c * 16;                                                              \
      __builtin_amdgcn_global_load_lds(                                                      \
          (const __attribute__((address_space(1))) void*)(&A[(size_t)(m0 + rg + lrow) * K + (kt) + lcol]), \
          (__attribute__((address_space(3))) void*)(&As[buf][rg * 32]), 16, 0, 0);           \
      __builtin_amdgcn_global_load_lds(                                                      \
          (const __attribute__((address_space(1))) void*)(&Bt[(size_t)(n0 + rg + lrow) * K + (kt) + lcol]), \
          (__attribute__((address_space(3))) void*)(&Bs[buf][rg * 32]), 16, 0, 0);           \
    }                                                                                        \
  }

  f32x4 zero = {0.f, 0.f, 0.f, 0.f};
  f32x4 acc[4][4];
#pragma unroll
  for (int i = 0; i < 4; ++i)
#pragma unroll
    for (int n = 0; n < 4; ++n) acc[i][n] = zero;

  int nkt = K >> 5;
  STAGE_GEMM(0, 0);
  __syncthreads();
  int cur = 0;
  for (int kt = 0; kt < nkt; ++kt) {
    if (kt + 1 < nkt) STAGE_GEMM(cur ^ 1, (kt + 1) << 5);
    short8 af[4], bfr[4];
#pragma unroll
    for (int i = 0; i < 4; ++i)
      af[i] = *reinterpret_cast<const short8*>(&As[cur][(wr * 64 + i * 16 + r16) * 32 + g * 8]);
#pragma unroll
    for (int i = 0; i < 4; ++i)
      bfr[i] = *reinterpret_cast<const short8*>(&Bs[cur][(wc * 64 + i * 16 + r16) * 32 + g * 8]);
#pragma unroll
    for (int i = 0; i < 4; ++i)
#pragma unroll
      for (int n = 0; n < 4; ++n)
        acc[i][n] = __builtin_amdgcn_mfma_f32_16x16x32_bf16(af[i], bfr[n], acc[i][n], 0, 0, 0);
    __syncthreads();   // drains vmcnt(0)+lgkm(0): staged tile ready, reads done
    cur ^= 1;
  }
#undef STAGE_GEMM

#pragma unroll
  for (int i = 0; i < 4; ++i)
#pragma unroll
    for (int n = 0; n < 4; ++n)
#pragma unroll
      for (int j = 0; j < 4; ++j) {
        int row = m0 + wr * 64 + i * 16 + g * 4 + j;
        int col = n0 + wc * 64 + n * 16 + r16;
        float val = acc[i][n][j] + bias[col];
        if (MODE == 0) {
          outF[(size_t)row * N + col] = val;
        } else {
          int which = col >> 10, c = col & 1023;
          int h = c >> 6, d = c & 63;
          int b = row >> 11, t = row & 2047;
          if (which == 2) {
            // sigma-permute key index within its 32-block
            int k5 = t & 31;
            int p = (k5 < 16) ? ((k5 >> 2) * 8 + (k5 & 3))
                              : (((k5 - 16) >> 2) * 8 + 4 + ((k5 - 16) & 3));
            int tp = (t & ~31) | p;
            outQKV[2 * (size_t)QKV_ELEMS +
                   (((size_t)(b * 16 + h) * 64 + d) * 2048 + tp)] = bf16_of(val);
          } else {
            if (which == 0) val *= 0.125f;   // fold 1/sqrt(HS) into Q (exact pow2)
            outQKV[(size_t)which * QKV_ELEMS +
                   (((size_t)(b * 16 + h) * 2048 + t) * 64 + d)] = bf16_of(val);
          }
        }
      }
}

// ---------------- causal flash attention (R12 compute, bh->XCD locality remap) --------
// 64-row q-block per wave, 4-strip reuse, sigma-permuted V, own-lane P frags.
// Remap so XCD(dispatch id % 8) == bh % 8: each XCD's L2 serves 8 heads = 4 MB K/V.
struct Frags {
  short8 kf0[2], kf1[2], vf[4];
};

static __device__ __forceinline__ void load_frags(Frags& f, int key0, int r16, int g4,
                                                  const unsigned short* __restrict__ Kp,
                                                  const unsigned short* __restrict__ Vp) {
#pragma unroll
  for (int c = 0; c < 2; ++c)
    f.kf0[c] = *reinterpret_cast<const short8*>(&Kp[(size_t)(key0 + r16) * 64 + c * 32 + g4 * 8]);
#pragma unroll
  for (int c = 0; c < 2; ++c)
    f.kf1[c] = *reinterpret_cast<const short8*>(&Kp[(size_t)(key0 + 16 + r16) * 64 + c * 32 + g4 * 8]);
#pragma unroll
  for (int dblk = 0; dblk < 4; ++dblk)
    f.vf[dblk] = *reinterpret_cast<const short8*>(
        &Vp[(size_t)(dblk * 16 + r16) * TT + key0 + g4 * 8]);  // sigma order
}

// MODE 0: full 32-key tile. MODE 1: kb0 full + kb1 diag. MODE 2: kb0 diag only.
template <int MODE>
static __device__ __forceinline__ void compute_tile(const Frags& f, int r16, int g4,
                                                    const short8 qf[2], f32x4 o[4],
                                                    float& m, float& lsum) {
  f32x4 zero = {0.f, 0.f, 0.f, 0.f};
  f32x4 s0 = zero, s1 = zero;
  __builtin_amdgcn_s_setprio(1);
  s0 = __builtin_amdgcn_mfma_f32_16x16x32_bf16(f.kf0[0], qf[0], s0, 0, 0, 0);
  s0 = __builtin_amdgcn_mfma_f32_16x16x32_bf16(f.kf0[1], qf[1], s0, 0, 0, 0);
  if (MODE != 2) {
    s1 = __builtin_amdgcn_mfma_f32_16x16x32_bf16(f.kf1[0], qf[0], s1, 0, 0, 0);
    s1 = __builtin_amdgcn_mfma_f32_16x16x32_bf16(f.kf1[1], qf[1], s1, 0, 0, 0);
  }
  __builtin_amdgcn_s_setprio(0);

  if (MODE == 2) {
#pragma unroll
    for (int r = 0; r < 4; ++r)
      if (g4 * 4 + r > r16) s0[r] = -1e30f;
  }
  if (MODE == 1) {
#pragma unroll
    for (int r = 0; r < 4; ++r)
      if (g4 * 4 + r > r16) s1[r] = -1e30f;
  }

  float om = fmaxf(fmaxf(s0[0], s0[1]), fmaxf(s0[2], s0[3]));
  if (MODE != 2)
    om = fmaxf(om, fmaxf(fmaxf(s1[0], s1[1]), fmaxf(s1[2], s1[3])));
  om = fmaxf(om, __shfl_xor(om, 16));
  om = fmaxf(om, __shfl_xor(om, 32));
  float mn = fmaxf(m, om);
  float alpha = __expf(m - mn);
  m = mn;

  float p0[4], p1[4];
#pragma unroll
  for (int r = 0; r < 4; ++r) {
    p0[r] = __expf(s0[r] - mn);
    if (MODE != 2) p1[r] = __expf(s1[r] - mn);
  }
  float rs = (p0[0] + p0[1]) + (p0[2] + p0[3]);
  if (MODE != 2) rs += (p1[0] + p1[1]) + (p1[2] + p1[3]);
  rs += __shfl_xor(rs, 16);
  rs += __shfl_xor(rs, 32);
  lsum = lsum * alpha + rs;
#pragma unroll
  for (int dblk = 0; dblk < 4; ++dblk)
#pragma unroll
    for (int r = 0; r < 4; ++r) o[dblk][r] *= alpha;

  // P B-fragment from the lane's OWN values (sigma key order, matches V layout)
  union { int w[4]; short8 s8; } pf;
  CVTPK(pf.w[0], p0[0], p0[1]);
  CVTPK(pf.w[1], p0[2], p0[3]);
  if (MODE != 2) {
    CVTPK(pf.w[2], p1[0], p1[1]);
    CVTPK(pf.w[3], p1[2], p1[3]);
  } else {
    pf.w[2] = 0; pf.w[3] = 0;
  }

  __builtin_amdgcn_s_setprio(1);
#pragma unroll
  for (int dblk = 0; dblk < 4; ++dblk)
    o[dblk] = __builtin_amdgcn_mfma_f32_16x16x32_bf16(f.vf[dblk], pf.s8, o[dblk], 0, 0, 0);
  __builtin_amdgcn_s_setprio(0);
}

__global__ __launch_bounds__(64, 2) void attn_kernel(const unsigned short* __restrict__ Qm,
                                                     const unsigned short* __restrict__ Km,
                                                     const unsigned short* __restrict__ Vt,
                                                     unsigned short* __restrict__ Y) {
  int lane = threadIdx.x;
  int r16 = lane & 15, g4 = lane >> 4;

  // bh->XCD remap: dispatch id % 8 == bh % 8; heavy q-blocks dispatched first.
  int flat = (int)(blockIdx.y * gridDim.x + blockIdx.x);  // 0..2047
  int u = flat >> 3;
  int bh = (flat & 7) + 8 * (u & 7);
  int a = 31 - (u >> 3);
  int Q0 = a * 64;

  const unsigned short* Qp = Qm + (size_t)bh * TT * HSS;
  const unsigned short* Kp = Km + (size_t)bh * TT * HSS;
  const unsigned short* Vp = Vt + (size_t)bh * HSS * TT;

  // Q fragments for 4 strips (rows Q0+16ss+r16)
  short8 qf[4][2];
#pragma unroll
  for (int ss = 0; ss < 4; ++ss)
#pragma unroll
    for (int c = 0; c < 2; ++c)
      qf[ss][c] = *reinterpret_cast<const short8*>(
          &Qp[(size_t)(Q0 + ss * 16 + r16) * 64 + c * 32 + g4 * 8]);

  f32x4 o[4][4];
#pragma unroll
  for (int ss = 0; ss < 4; ++ss)
#pragma unroll
    for (int dblk = 0; dblk < 4; ++dblk) o[ss][dblk] = f32x4{0.f, 0.f, 0.f, 0.f};
  float m[4] = {-1e30f, -1e30f, -1e30f, -1e30f};
  float l[4] = {0.f, 0.f, 0.f, 0.f};

  Frags F;
  // tiles full for all 4 strips: t = 0 .. 2a-1
  int nfull = a * 2;
  for (int t = 0; t < nfull; ++t) {
    load_frags(F, t << 5, r16, g4, Kp, Vp);
#pragma unroll
    for (int ss = 0; ss < 4; ++ss)
      compute_tile<0>(F, r16, g4, qf[ss], o[ss], m[ss], l[ss]);
  }
  // tile 2a (key0 = Q0): ss0 diag(M2), ss1 M1, ss2/ss3 full
  load_frags(F, Q0, r16, g4, Kp, Vp);
  compute_tile<2>(F, r16, g4, qf[0], o[0], m[0], l[0]);
  compute_tile<1>(F, r16, g4, qf[1], o[1], m[1], l[1]);
  compute_tile<0>(F, r16, g4, qf[2], o[2], m[2], l[2]);
  compute_tile<0>(F, r16, g4, qf[3], o[3], m[3], l[3]);
  // tile 2a+1 (key0 = Q0+32): ss2 M2, ss3 M1
  load_frags(F, Q0 + 32, r16, g4, Kp, Vp);
  compute_tile<2>(F, r16, g4, qf[2], o[2], m[2], l[2]);
  compute_tile<1>(F, r16, g4, qf[3], o[3], m[3], l[3]);

  // epilogue
  int b = bh >> 4, h = bh & 15;
#pragma unroll
  for (int ss = 0; ss < 4; ++ss) {
    float inv = 1.0f / l[ss];
    unsigned short* yrow = Y + ((size_t)(b * TT + Q0 + ss * 16 + r16) * CCH) + h * 64;
#pragma unroll
    for (int dblk = 0; dblk < 4; ++dblk) {
      float v0 = o[ss][dblk][0] * inv, v1 = o[ss][dblk][1] * inv;
      float v2 = o[ss][dblk][2] * inv, v3 = o[ss][dblk][3] * inv;
      int wa, wb;
      CVTPK(wa, v0, v1);
      CVTPK(wb, v2, v3);
      int2 pk; pk.x = wa; pk.y = wb;
      *reinterpret_cast<int2*>(&yrow[dblk * 16 + g4 * 4]) = pk;
    }
  }
}

// ---------------- host ----------------
extern "C" void kernel_launch(void* const* d_in, const int* in_sizes, int n_in,
                              void* d_out, int out_size, void* d_ws, size_t ws_size,
                              hipStream_t stream) {
  const float* x      = (const float*)d_in[0];
  const float* w_attn = (const float*)d_in[1];
  const float* b_attn = (const float*)d_in[2];
  const float* w_proj = (const float*)d_in[3];
  const float* b_proj = (const float*)d_in[4];
  float* out = (float*)d_out;

  char* ws = (char*)d_ws;
  unsigned short* xb  = (unsigned short*)(ws + 0);          // 8192x1024 bf16; reused as Y
  unsigned short* wta = (unsigned short*)(ws + 16777216);   // 3072x1024 bf16
  unsigned short* wtp = (unsigned short*)(ws + 23068672);   // 1024x1024 bf16
  unsigned short* qb  = (unsigned short*)(ws + 25165824);   // q,k: [64][2048][64]; vt(sigma): [64][64][2048]
  unsigned short* yb  = xb;

  cast_f32_bf16<<<(MROWS * CCH) / 1024, 256, 0, stream>>>(x, xb, MROWS * CCH);
  transpose_cast<<<dim3(3 * CCH / 32, CCH / 32), 256, 0, stream>>>(w_attn, wta, CCH, 3 * CCH);
  transpose_cast<<<dim3(CCH / 32, CCH / 32), 256, 0, stream>>>(w_proj, wtp, CCH, CCH);

  {
    dim3 grid(3 * CCH / 128, MROWS / 128);   // 24 x 64 = 1536 (%8==0)
    gemm_bt<1><<<grid, 256, 0, stream>>>(xb, wta, b_attn, nullptr, qb, MROWS, 3 * CCH, CCH);
  }
  {
    dim3 grid(TT / 64, BB * NHH);   // 2048 single-wave blocks (remapped in-kernel)
    attn_kernel<<<grid, 64, 0, stream>>>(qb, qb + (size_t)QKV_ELEMS, qb + 2 * (size_t)QKV_ELEMS, yb);
  }
  {
    dim3 grid(CCH / 128, MROWS / 128);       // 8 x 64 = 512 (%8==0)
    gemm_bt<0><<<grid, 256, 0, stream>>>(yb, wtp, b_proj, out, nullptr, MROWS, CCH, CCH);
  }
}